// Round 2
// baseline (1154.186 us; speedup 1.0000x reference)
//
#include <hip/hip_runtime.h>
#include <hip/hip_bf16.h>
#include <stdint.h>

#define LN_EPS 1e-5f

typedef __attribute__((ext_vector_type(8))) __bf16 bf16x8;
typedef __attribute__((ext_vector_type(8))) short short8;
typedef __attribute__((ext_vector_type(4))) float floatx4;

__device__ __forceinline__ ushort f2bf(float f) {
    __hip_bfloat16 h = __float2bfloat16(f);
    return *reinterpret_cast<ushort*>(&h);
}
__device__ __forceinline__ float bf2f(ushort u) {
    return __builtin_bit_cast(float, ((unsigned int)u) << 16);
}

// async global->LDS, 16B per lane; LDS dest = wave-uniform base + lane*16
__device__ __forceinline__ void gload16(const void* g, void* l) {
#if __has_builtin(__builtin_amdgcn_global_load_lds)
    __builtin_amdgcn_global_load_lds(
        (const __attribute__((address_space(1))) unsigned int*)g,
        (__attribute__((address_space(3))) unsigned int*)l, 16, 0, 0);
#else
    *(int4*)l = *(const int4*)g;
#endif
}

#define SBAR __builtin_amdgcn_s_barrier()
#define SCHED0 __builtin_amdgcn_sched_barrier(0)
#define WAIT_VM8 asm volatile("s_waitcnt vmcnt(8)" ::: "memory")
#define WAIT_VM4 asm volatile("s_waitcnt vmcnt(4)" ::: "memory")
#define WAIT_VM0 asm volatile("s_waitcnt vmcnt(0)" ::: "memory")

// ---------------------------------------------------------------------------
// GEMM: C[M,N] = A[M,K](bf16 rm, lda) x Bt[N,K](bf16 rm, ldb)  (Bt = B^T)
// 128x128 tile, BK=32, 256 thr (4 waves 2Mx2N, 64x64 out each), mfma
// 16x16x32 bf16. Triple-buffered fragment-order LDS (48 KiB static ->
// 3 blocks/CU for inter-block overlap of prologue/epilogue with MFMA),
// prefetch depth 2 tiles, counted vmcnt (8 steady state, never 0 mid-loop),
// 2 barriers/tile, XCD-chunked block swizzle (requires nwg%8==0).
// LDS buffer (8192 ushorts): A frags [0..4096), B frags [4096..8192);
// frag-order slot: off = frag*512 + quad*128 + l16*8  (16B per lane,
// contiguous 1024B per wave read -> conflict-free ds_read_b128).
// Requires M%128==0, N%128==0, K%64==0 (true for all call sites).
// EPI: 0 bf16 | 1 bf16 sigmoid | 2 bf16 relu^2 | 3 f32 out=add0+mul0*acc
// ---------------------------------------------------------------------------
template <int EPI>
__global__ __launch_bounds__(256, 3) void gemm128(
    const ushort* __restrict__ A, const ushort* __restrict__ Bt,
    int K, int lda, int ldb, int ldc,
    float* __restrict__ outF, ushort* __restrict__ outB,
    const float* __restrict__ add0, const ushort* __restrict__ mul0) {
    __shared__ __align__(16) ushort lds[3 * 8192];

    const int tid  = threadIdx.x;
    const int lane = tid & 63;
    const int quad = lane >> 4;
    const int l16  = lane & 15;
    const int wv   = tid >> 6;      // 0..3
    const int wmi  = wv >> 1;       // 0..1 -> rows wmi*64
    const int wni  = wv & 1;        // 0..1 -> cols wni*64

    // XCD-chunked swizzle (bijective since all grids have nwg%8==0)
    const int gx  = gridDim.x;
    const int nwg = gx * gridDim.y;
    int bid = blockIdx.y * gx + blockIdx.x;
    bid = (bid & 7) * (nwg >> 3) + (bid >> 3);
    const long m0 = (long)(bid / gx) * 128;
    const long n0 = (long)(bid % gx) * 128;

    floatx4 acc[4][4];
#pragma unroll
    for (int i = 0; i < 4; ++i)
#pragma unroll
        for (int j = 0; j < 4; ++j) acc[i][j] = (floatx4)0.f;

    // staging decode: 16B slot j -> row = (j>>6)*16 + (j&15), col = ((j>>4)&3)*8
    const int rs = ((tid >> 6) << 4) + (tid & 15);
    const int cs = ((tid >> 4) & 3) * 8;
    const ushort* aP0 = A + (m0 + rs) * (long)lda + cs;
    const ushort* aP1 = aP0 + 64 * (long)lda;
    const ushort* bP0 = Bt + (n0 + rs) * (long)ldb + cs;
    const ushort* bP1 = bP0 + 64 * (long)ldb;
    const int dA0 = tid * 8, dA1 = tid * 8 + 2048;
    const int dB0 = 4096 + tid * 8, dB1 = 4096 + tid * 8 + 2048;

    const int aoff = quad * 128 + l16 * 8;   // ushort units within a frag
    const int NT = K >> 5;

#define STAGE128(t, sl)                                                       \
    do {                                                                      \
        const long _ko = (long)(t) * 32;                                      \
        ushort* _d = &lds[(sl) * 8192];                                       \
        gload16(aP0 + _ko, _d + dA0);                                         \
        gload16(aP1 + _ko, _d + dA1);                                         \
        gload16(bP0 + _ko, _d + dB0);                                         \
        gload16(bP1 + _ko, _d + dB1);                                         \
    } while (0)

    // prologue: prefetch tiles 0 and 1
    STAGE128(0, 0);
    STAGE128(1, 1);

    int sl = 0;   // t % 3
    int st = 2;   // (t+2) % 3
    for (int t = 0; t < NT; ++t) {
        SBAR;      // all waves done reading slot st (== (t-1)%3) -> safe to overwrite
        SCHED0;
        if (t + 2 < NT) {
            STAGE128(t + 2, st);
            WAIT_VM8;          // drain tile t's 4 loads (t+1,t+2 stay in flight)
        } else if (t + 1 < NT) {
            WAIT_VM4;          // tail: only t+1 in flight
        } else {
            WAIT_VM0;
        }
        SBAR;      // slot sl data visible to all waves
        SCHED0;

        const ushort* buf = &lds[sl * 8192];
        bf16x8 a[4], b[4];
#pragma unroll
        for (int mi = 0; mi < 4; ++mi)
            a[mi] = __builtin_bit_cast(
                bf16x8, *(const short8*)&buf[(wmi * 4 + mi) * 512 + aoff]);
#pragma unroll
        for (int ni = 0; ni < 4; ++ni)
            b[ni] = __builtin_bit_cast(
                bf16x8, *(const short8*)&buf[4096 + (wni * 4 + ni) * 512 + aoff]);

        __builtin_amdgcn_s_setprio(1);
#pragma unroll
        for (int mi = 0; mi < 4; ++mi)
#pragma unroll
            for (int ni = 0; ni < 4; ++ni)
                acc[mi][ni] = __builtin_amdgcn_mfma_f32_16x16x32_bf16(
                    a[mi], b[ni], acc[mi][ni], 0, 0, 0);
        __builtin_amdgcn_s_setprio(0);
        SCHED0;

        sl = (sl == 2) ? 0 : sl + 1;
        st = (st == 2) ? 0 : st + 1;
    }

    // C/D layout: col = lane&15, row = quad*4 + reg (m89/m91-verified)
#pragma unroll
    for (int mi = 0; mi < 4; ++mi) {
#pragma unroll
        for (int ni = 0; ni < 4; ++ni) {
            const long n = n0 + wni * 64 + ni * 16 + l16;
#pragma unroll
            for (int r = 0; r < 4; ++r) {
                const long m = m0 + wmi * 64 + mi * 16 + quad * 4 + r;
                const long idx = m * (long)ldc + n;
                float v = acc[mi][ni][r];
                if constexpr (EPI == 0) {
                    outB[idx] = f2bf(v);
                } else if constexpr (EPI == 1) {
                    outB[idx] = f2bf(1.f / (1.f + __expf(-v)));
                } else if constexpr (EPI == 2) {
                    float t = fmaxf(v, 0.f);
                    outB[idx] = f2bf(t * t);
                } else if constexpr (EPI == 3) {
                    outF[idx] = add0[idx] + bf2f(mul0[idx]) * v;
                }
            }
        }
    }
#undef STAGE128
}

// ---------------------------------------------------------------------------
// Fused LayerNorm + time-shift + mix -> bf16 outputs (3 mixes), f32 input.
// ---------------------------------------------------------------------------
__global__ __launch_bounds__(256) void ln_mix3(
    const float* __restrict__ x, const float* __restrict__ g,
    const float* __restrict__ be,
    const float* __restrict__ mx0, const float* __restrict__ mx1,
    const float* __restrict__ mx2,
    ushort* __restrict__ o0, ushort* __restrict__ o1, ushort* __restrict__ o2,
    int T, int C) {
    const long row = blockIdx.x;
    const int t = (int)(row % T);
    const int tid = threadIdx.x;
    const int i0 = tid * 4;

    floatx4 xc = *(const floatx4*)&x[row * C + i0];
    floatx4 xp = (floatx4)0.f;
    if (t > 0) xp = *(const floatx4*)&x[(row - 1) * C + i0];

    float sc = xc.x + xc.y + xc.z + xc.w;
    float qc = xc.x * xc.x + xc.y * xc.y + xc.z * xc.z + xc.w * xc.w;
    float sp = xp.x + xp.y + xp.z + xp.w;
    float qp = xp.x * xp.x + xp.y * xp.y + xp.z * xp.z + xp.w * xp.w;

#pragma unroll
    for (int off = 32; off; off >>= 1) {
        sc += __shfl_xor(sc, off);
        qc += __shfl_xor(qc, off);
        sp += __shfl_xor(sp, off);
        qp += __shfl_xor(qp, off);
    }
    __shared__ float part[4][4];
    const int wv = tid >> 6;
    if ((tid & 63) == 0) {
        part[wv][0] = sc; part[wv][1] = qc; part[wv][2] = sp; part[wv][3] = qp;
    }
    __syncthreads();
    sc = part[0][0] + part[1][0] + part[2][0] + part[3][0];
    qc = part[0][1] + part[1][1] + part[2][1] + part[3][1];
    sp = part[0][2] + part[1][2] + part[2][2] + part[3][2];
    qp = part[0][3] + part[1][3] + part[2][3] + part[3][3];

    const float invC = 1.f / (float)C;
    float muc = sc * invC;
    float rsc = rsqrtf(qc * invC - muc * muc + LN_EPS);
    float mup = sp * invC;
    float rsp = rsqrtf(qp * invC - mup * mup + LN_EPS);

    floatx4 gv = *(const floatx4*)&g[i0];
    floatx4 bv = *(const floatx4*)&be[i0];
    floatx4 hc = (xc - muc) * rsc * gv + bv;
    floatx4 hp = (floatx4)0.f;
    if (t > 0) hp = (xp - mup) * rsp * gv + bv;

    {
        floatx4 mk = *(const floatx4*)&mx0[i0];
        floatx4 v = hc * mk + hp * (1.f - mk);
        ushort4 pk;
        pk.x = f2bf(v.x); pk.y = f2bf(v.y); pk.z = f2bf(v.z); pk.w = f2bf(v.w);
        *(ushort4*)&o0[row * C + i0] = pk;
    }
    {
        floatx4 mk = *(const floatx4*)&mx1[i0];
        floatx4 v = hc * mk + hp * (1.f - mk);
        ushort4 pk;
        pk.x = f2bf(v.x); pk.y = f2bf(v.y); pk.z = f2bf(v.z); pk.w = f2bf(v.w);
        *(ushort4*)&o1[row * C + i0] = pk;
    }
    {
        floatx4 mk = *(const floatx4*)&mx2[i0];
        floatx4 v = hc * mk + hp * (1.f - mk);
        ushort4 pk;
        pk.x = f2bf(v.x); pk.y = f2bf(v.y); pk.z = f2bf(v.z); pk.w = f2bf(v.w);
        *(ushort4*)&o2[row * C + i0] = pk;
    }
}

// ---------------------------------------------------------------------------
// Fused: out = x + ry (residual), then LayerNorm(out) + shift + 2 mixes.
// ---------------------------------------------------------------------------
__global__ __launch_bounds__(256) void ln_mix_add(
    const float* __restrict__ x, const ushort* __restrict__ ry,
    const float* __restrict__ g, const float* __restrict__ be,
    const float* __restrict__ mx0, const float* __restrict__ mx1,
    float* __restrict__ outx,
    ushort* __restrict__ o0, ushort* __restrict__ o1, int T, int C) {
    const long row = blockIdx.x;
    const int t = (int)(row % T);
    const int tid = threadIdx.x;
    const int i0 = tid * 4;

    floatx4 xc = *(const floatx4*)&x[row * C + i0];
    ushort4 rc = *(const ushort4*)&ry[row * C + i0];
    xc.x += bf2f(rc.x); xc.y += bf2f(rc.y); xc.z += bf2f(rc.z); xc.w += bf2f(rc.w);
    *(floatx4*)&outx[row * C + i0] = xc;

    floatx4 xp = (floatx4)0.f;
    if (t > 0) {
        xp = *(const floatx4*)&x[(row - 1) * C + i0];
        ushort4 rp = *(const ushort4*)&ry[(row - 1) * C + i0];
        xp.x += bf2f(rp.x); xp.y += bf2f(rp.y); xp.z += bf2f(rp.z); xp.w += bf2f(rp.w);
    }

    float sc = xc.x + xc.y + xc.z + xc.w;
    float qc = xc.x * xc.x + xc.y * xc.y + xc.z * xc.z + xc.w * xc.w;
    float sp = xp.x + xp.y + xp.z + xp.w;
    float qp = xp.x * xp.x + xp.y * xp.y + xp.z * xp.z + xp.w * xp.w;

#pragma unroll
    for (int off = 32; off; off >>= 1) {
        sc += __shfl_xor(sc, off);
        qc += __shfl_xor(qc, off);
        sp += __shfl_xor(sp, off);
        qp += __shfl_xor(qp, off);
    }
    __shared__ float part[4][4];
    const int wv = tid >> 6;
    if ((tid & 63) == 0) {
        part[wv][0] = sc; part[wv][1] = qc; part[wv][2] = sp; part[wv][3] = qp;
    }
    __syncthreads();
    sc = part[0][0] + part[1][0] + part[2][0] + part[3][0];
    qc = part[0][1] + part[1][1] + part[2][1] + part[3][1];
    sp = part[0][2] + part[1][2] + part[2][2] + part[3][2];
    qp = part[0][3] + part[1][3] + part[2][3] + part[3][3];

    const float invC = 1.f / (float)C;
    float muc = sc * invC;
    float rsc = rsqrtf(qc * invC - muc * muc + LN_EPS);
    float mup = sp * invC;
    float rsp = rsqrtf(qp * invC - mup * mup + LN_EPS);

    floatx4 gv = *(const floatx4*)&g[i0];
    floatx4 bv = *(const floatx4*)&be[i0];
    floatx4 hc = (xc - muc) * rsc * gv + bv;
    floatx4 hp = (floatx4)0.f;
    if (t > 0) hp = (xp - mup) * rsp * gv + bv;

    {
        floatx4 mk = *(const floatx4*)&mx0[i0];
        floatx4 v = hc * mk + hp * (1.f - mk);
        ushort4 pk;
        pk.x = f2bf(v.x); pk.y = f2bf(v.y); pk.z = f2bf(v.z); pk.w = f2bf(v.w);
        *(ushort4*)&o0[row * C + i0] = pk;
    }
    {
        floatx4 mk = *(const floatx4*)&mx1[i0];
        floatx4 v = hc * mk + hp * (1.f - mk);
        ushort4 pk;
        pk.x = f2bf(v.x); pk.y = f2bf(v.y); pk.z = f2bf(v.z); pk.w = f2bf(v.w);
        *(ushort4*)&o1[row * C + i0] = pk;
    }
}

// ===========================================================================
// Segmented exact WKV scan. T split into SEG segments of L steps.
// ===========================================================================

// K1: per-segment pp from zero state (reads k only)
__global__ __launch_bounds__(256) void wkv_pp_local(
    const float* __restrict__ w, const ushort* __restrict__ k,
    float* __restrict__ pp_loc, int C, int L) {
    const int g = blockIdx.x * 256 + threadIdx.x;
    const int c = g % C;
    const long seg = g / C;
    const float L2E = 1.4426950408889634f;
    const float w2 = w[c] * L2E;
    const ushort* kp = k + seg * L * C + c;
    float pp = -1e38f;
    for (int j = 0; j < L; ++j) {
        float kk = bf2f(kp[(long)j * C]) * L2E;
        float ppw = pp + w2;
        float wk = w2 + kk;
        float p2 = fmaxf(ppw, wk);
        pp = p2 + log2f(exp2f(ppw - p2) + exp2f(wk - p2));
    }
    pp_loc[g] = pp;
}

// K2: sequential pp composition per channel
__global__ __launch_bounds__(256) void wkv_pp_compose(
    const float* __restrict__ w, const float* __restrict__ pp_loc,
    float* __restrict__ pp_in, int C, int SEG, int L) {
    const int g = blockIdx.x * 256 + threadIdx.x;  // b*C + c
    const int c = g % C;
    const long b = g / C;
    const float wL = w[c] * 1.4426950408889634f * (float)L;
    float pp = -1e38f;
    for (int s = 0; s < SEG; ++s) {
        const long idx = (b * SEG + s) * C + c;
        pp_in[idx] = pp;
        float lhs = pp + wL;
        float rhs = pp_loc[idx];
        float m = fmaxf(lhs, rhs);
        pp = m + log2f(exp2f(lhs - m) + exp2f(rhs - m));
    }
}

// K3: per-segment (alpha,beta) on the TRUE pp path
__global__ __launch_bounds__(256) void wkv_ab_local(
    const float* __restrict__ w, const ushort* __restrict__ k,
    const ushort* __restrict__ v, const float* __restrict__ pp_in,
    float* __restrict__ alpha, float* __restrict__ beta, int C, int L) {
    const int g = blockIdx.x * 256 + threadIdx.x;
    const int c = g % C;
    const long seg = g / C;
    const float L2E = 1.4426950408889634f;
    const float w2 = w[c] * L2E;
    const ushort* kp = k + seg * L * C + c;
    const ushort* vp = v + seg * L * C + c;
    float pp = pp_in[g];
    float al = 1.f, be = 0.f;
    for (int j = 0; j < L; ++j) {
        float kk = bf2f(kp[(long)j * C]) * L2E;
        float vv = bf2f(vp[(long)j * C]);
        float ppw = pp + w2;
        float wk = w2 + kk;
        float p2 = fmaxf(ppw, wk);
        float e1u = exp2f(ppw - p2);
        float e2u = exp2f(wk - p2);
        al *= e1u;
        be = e1u * be + e2u * vv;
        pp = p2 + log2f(e1u + e2u);
    }
    alpha[g] = al;
    beta[g] = be;
}

// K4: sequential aa composition per channel
__global__ __launch_bounds__(256) void wkv_aa_compose(
    const float* __restrict__ alpha, const float* __restrict__ beta,
    float* __restrict__ aa_in, int C, int SEG) {
    const int g = blockIdx.x * 256 + threadIdx.x;  // b*C + c
    const int c = g % C;
    const long b = g / C;
    float aa = 0.f;
    for (int s = 0; s < SEG; ++s) {
        const long idx = (b * SEG + s) * C + c;
        aa_in[idx] = aa;
        aa = alpha[idx] * aa + beta[idx];
    }
    (void)c;
}

// K5: per-segment emit with true incoming state: ry = r * y, [M][C] layout
__global__ __launch_bounds__(256) void wkv_emit(
    const float* __restrict__ w, const float* __restrict__ u,
    const ushort* __restrict__ k, const ushort* __restrict__ v,
    const ushort* __restrict__ r, const float* __restrict__ aa_in,
    const float* __restrict__ pp_in, ushort* __restrict__ ry, int C, int L) {
    const int g = blockIdx.x * 256 + threadIdx.x;
    const int c = g % C;
    const long seg = g / C;
    const float L2E = 1.4426950408889634f;
    const float w2 = w[c] * L2E;
    const float u2 = u[c] * L2E;
    const long base = seg * L * C + c;
    const ushort* kp = k + base;
    const ushort* vp = v + base;
    const ushort* rp = r + base;
    ushort* op = ry + base;
    float aa = aa_in[g];
    float pp = pp_in[g];
    for (int j = 0; j < L; ++j) {
        const long o = (long)j * C;
        float kk = bf2f(kp[o]) * L2E;
        float vv = bf2f(vp[o]);
        float uk = u2 + kk;
        float p = fmaxf(pp, uk);
        float e1 = exp2f(pp - p);
        float e2 = exp2f(uk - p);
        float y = __fdividef(e1 * aa + e2 * vv, e1 + e2);
        op[o] = f2bf(bf2f(rp[o]) * y);
        float ppw = pp + w2;
        float wk = w2 + kk;
        float p2 = fmaxf(ppw, wk);
        float e1u = exp2f(ppw - p2);
        float e2u = exp2f(wk - p2);
        aa = e1u * aa + e2u * vv;
        pp = p2 + log2f(e1u + e2u);
    }
}

// out[n][k] = bf16(in[k][n]); in is [K][N] fp32 row-major. block (32,8).
__global__ __launch_bounds__(256) void transpose_bf16(
    const float* __restrict__ in, ushort* __restrict__ out, int K, int N) {
    __shared__ float tile[32][33];
    const int tx = threadIdx.x, ty = threadIdx.y;
    const long k0 = (long)blockIdx.y * 32, n0 = (long)blockIdx.x * 32;
#pragma unroll
    for (int i = 0; i < 4; i++)
        tile[ty + i * 8][tx] = in[(k0 + ty + i * 8) * N + n0 + tx];
    __syncthreads();
#pragma unroll
    for (int i = 0; i < 4; i++)
        out[(n0 + ty + i * 8) * K + k0 + tx] = f2bf(tile[tx][ty + i * 8]);
}

extern "C" void kernel_launch(void* const* d_in, const int* in_sizes, int n_in,
                              void* d_out, int out_size, void* d_ws, size_t ws_size,
                              hipStream_t stream) {
    const float* x      = (const float*)d_in[0];
    const float* tdecay = (const float*)d_in[1];
    const float* tfirst = (const float*)d_in[2];
    const float* w_tk   = (const float*)d_in[3];
    const float* w_tv   = (const float*)d_in[4];
    const float* w_tr   = (const float*)d_in[5];
    const float* w_ck   = (const float*)d_in[6];
    const float* w_cv   = (const float*)d_in[7];
    const float* w_cr   = (const float*)d_in[8];
    const float* ln1g   = (const float*)d_in[9];
    const float* ln1b   = (const float*)d_in[10];
    const float* ln2g   = (const float*)d_in[11];
    const float* ln2b   = (const float*)d_in[12];
    const float* mixk   = (const float*)d_in[13];
    const float* mixv   = (const float*)d_in[14];
    const float* mixr   = (const float*)d_in[15];
    const float* cmixk  = (const float*)d_in[16];
    const float* cmixr  = (const float*)d_in[17];
    float* out = (float*)d_out;

    const int C  = in_sizes[1];              // 1024
    const long M = (long)in_sizes[0] / C;    // 16384
    const int T  = 2048;
    const int B  = (int)(M / T);
    const int H  = 2 * C;                    // 2048 = half of 4C
    const int SEG = 64;                      // segments per sequence
    const int L  = T / SEG;                  // 32 steps per segment
    const int NSEG = B * SEG;                // 512 total segments

    // workspace layout identical to previous (verified) version
    const size_t MBy = 1024ull * 1024ull;
    char* w8 = (char*)d_ws;
    ushort* wT_tk  = (ushort*)(w8 + 0 * MBy);
    ushort* wT_tv  = (ushort*)(w8 + 2 * MBy);
    ushort* wT_tr  = (ushort*)(w8 + 4 * MBy);
    ushort* wT_cr  = (ushort*)(w8 + 6 * MBy);
    ushort* wT_ck  = (ushort*)(w8 + 8 * MBy);
    ushort* wT_cv0 = (ushort*)(w8 + 16 * MBy);
    ushort* wT_cv1 = (ushort*)(w8 + 20 * MBy);
    ushort* xk     = (ushort*)(w8 + 24 * MBy);
    ushort* xv     = (ushort*)(w8 + 56 * MBy);
    ushort* xr     = (ushort*)(w8 + 88 * MBy);
    ushort* kbuf   = (ushort*)(w8 + 120 * MBy);
    ushort* vbuf   = (ushort*)(w8 + 152 * MBy);
    ushort* rbuf   = (ushort*)(w8 + 24 * MBy);   // xk dead
    float*  pp_loc = (float*)(w8 + 56 * MBy);    // xv dead (2MB each)
    float*  pp_in  = (float*)(w8 + 58 * MBy);
    float*  alpha  = (float*)(w8 + 60 * MBy);
    float*  beta   = (float*)(w8 + 62 * MBy);
    float*  aa_in  = (float*)(w8 + 64 * MBy);
    ushort* ry     = (ushort*)(w8 + 88 * MBy);   // xr dead
    ushort* ck     = (ushort*)(w8 + 120 * MBy);  // kbuf dead
    ushort* cr     = (ushort*)(w8 + 152 * MBy);  // vbuf dead
    ushort* scr    = (ushort*)(w8 + 24 * MBy);   // rbuf dead
    ushort* kkbuf  = (ushort*)(w8 + 56 * MBy);   // states/ry dead, 64MB

    dim3 tb(32, 8);
    transpose_bf16<<<dim3(C / 32, C / 32), tb, 0, stream>>>(w_tk, wT_tk, C, C);
    transpose_bf16<<<dim3(C / 32, C / 32), tb, 0, stream>>>(w_tv, wT_tv, C, C);
    transpose_bf16<<<dim3(C / 32, C / 32), tb, 0, stream>>>(w_tr, wT_tr, C, C);
    transpose_bf16<<<dim3(C / 32, C / 32), tb, 0, stream>>>(w_cr, wT_cr, C, C);
    transpose_bf16<<<dim3(4 * C / 32, C / 32), tb, 0, stream>>>(w_ck, wT_ck, C, 4 * C);
    transpose_bf16<<<dim3(C / 32, H / 32), tb, 0, stream>>>(w_cv, wT_cv0, H, C);
    transpose_bf16<<<dim3(C / 32, H / 32), tb, 0, stream>>>(w_cv + (long)H * C, wT_cv1, H, C);

    ln_mix3<<<(int)M, 256, 0, stream>>>(x, ln1g, ln1b, mixk, mixv, mixr,
                                        xk, xv, xr, T, C);

    dim3 g128(C / 128, (int)(M / 128));          // 8 x 128 = 1024 blocks
    gemm128<0><<<g128, 256, 0, stream>>>(xk, wT_tk, C, C, C, C,
                                         nullptr, kbuf, nullptr, nullptr);
    gemm128<0><<<g128, 256, 0, stream>>>(xv, wT_tv, C, C, C, C,
                                         nullptr, vbuf, nullptr, nullptr);
    gemm128<1><<<g128, 256, 0, stream>>>(xr, wT_tr, C, C, C, C,
                                         nullptr, rbuf, nullptr, nullptr);

    // segmented exact WKV scan
    const int segthreads = NSEG * C;                     // 524288
    wkv_pp_local<<<segthreads / 256, 256, 0, stream>>>(tdecay, kbuf, pp_loc, C, L);
    wkv_pp_compose<<<(B * C) / 256, 256, 0, stream>>>(tdecay, pp_loc, pp_in, C, SEG, L);
    wkv_ab_local<<<segthreads / 256, 256, 0, stream>>>(tdecay, kbuf, vbuf, pp_in,
                                                       alpha, beta, C, L);
    wkv_aa_compose<<<(B * C) / 256, 256, 0, stream>>>(alpha, beta, aa_in, C, SEG);
    wkv_emit<<<segthreads / 256, 256, 0, stream>>>(tdecay, tfirst, kbuf, vbuf, rbuf,
                                                   aa_in, pp_in, ry, C, L);

    // fused: out = x + ry, then LN2 + shift + channel mixes
    ln_mix_add<<<(int)M, 256, 0, stream>>>(x, ry, ln2g, ln2b, cmixk, cmixr,
                                           out, ck, cr, T, C);

    gemm128<1><<<g128, 256, 0, stream>>>(cr, wT_cr, C, C, C, C,
                                         nullptr, scr, nullptr, nullptr);

    // channel-mix hidden (4C) processed in two 2C halves through one 64MB buffer
    for (int h = 0; h < 2; ++h) {
        const ushort* wck_h = wT_ck + (long)h * H * C;
        const ushort* wcv_h = (h == 0) ? wT_cv0 : wT_cv1;
        gemm128<2><<<dim3(H / 128, (int)(M / 128)), 256, 0, stream>>>(
            ck, wck_h, C, C, C, H, nullptr, kkbuf, nullptr, nullptr);
        gemm128<3><<<g128, 256, 0, stream>>>(
            kkbuf, wcv_h, H, H, H, C, out, nullptr, out, scr);
    }
}

// Round 7
// 900.122 us; speedup vs baseline: 1.2823x; 1.2823x over previous
//
#include <hip/hip_runtime.h>
#include <hip/hip_bf16.h>
#include <stdint.h>

#define LN_EPS 1e-5f

typedef __attribute__((ext_vector_type(8))) __bf16 bf16x8;
typedef __attribute__((ext_vector_type(8))) short short8;
typedef __attribute__((ext_vector_type(4))) float floatx4;

__device__ __forceinline__ ushort f2bf(float f) {
    __hip_bfloat16 h = __float2bfloat16(f);
    return *reinterpret_cast<ushort*>(&h);
}
__device__ __forceinline__ float bf2f(ushort u) {
    return __builtin_bit_cast(float, ((unsigned int)u) << 16);
}

// async global->LDS, 16B per lane; LDS dest = wave-uniform base + lane*16
__device__ __forceinline__ void gload16(const void* g, void* l) {
#if __has_builtin(__builtin_amdgcn_global_load_lds)
    __builtin_amdgcn_global_load_lds(
        (const __attribute__((address_space(1))) unsigned int*)g,
        (__attribute__((address_space(3))) unsigned int*)l, 16, 0, 0);
#else
    *(int4*)l = *(const int4*)g;
#endif
}

#define SBAR __builtin_amdgcn_s_barrier()
#define SCHED0 __builtin_amdgcn_sched_barrier(0)
#define WAIT_LGKM0 asm volatile("s_waitcnt lgkmcnt(0)" ::: "memory")
#define WAIT_VM4 asm volatile("s_waitcnt vmcnt(4)" ::: "memory")
#define WAIT_VM0 asm volatile("s_waitcnt vmcnt(0)" ::: "memory")

// ---------------------------------------------------------------------------
// GEMM: C[M,N] = A[M,K](bf16 rm, lda) x Bt[N,K](bf16 rm, ldb)  (Bt = B^T)
// 256x256 tile, BK=64, 512 thr (8 waves 2Mx4N, each 128x64 out), 8-phase
// schedule with counted vmcnt (T3+T4), conflict-free fragment-order LDS
// (T2-equivalent), setprio around MFMA clusters (T5). 128 KiB dynamic LDS,
// 1 block/CU. XCD-chunked bijective swizzle in COLUMN-major tile order so
// each XCD chunk covers ONE B(N)-panel (0.5-1MB, per-XCD-L2-resident) and a
// contiguous A row range. Requires M%256==0, N%256==0, K%64==0, nwg%8==0.
// LDS regions: [dbuf][A|B][half] x 16KiB. Fragment-order slot within a half:
//   slot(row,cchunk) = ((row>>4)*8 + c)*16 + (row&15), c -> cols (c&3)*8+(c>>2)*32
// so a wave's ds_read_b128 for one (mi,ks) fragment is contiguous 1024B.
// EPI: 0 bf16 | 1 bf16 sigmoid | 2 bf16 relu^2 | 3 f32 out=add0+mul0*acc
// ---------------------------------------------------------------------------
#define STAGE_A(h, t)                                                        \
    do {                                                                     \
        ushort* _d = &lds[((((t) & 1) * 2 + 0) * 2 + (h)) * 8192];           \
        const long _o = (long)(h) * 128 * lda + (long)(t) * 64;              \
        gload16(aS0 + _o, _d + tid * 8);                                     \
        gload16(aS1 + _o, _d + (tid + 512) * 8);                             \
    } while (0)
#define STAGE_B(h, t)                                                        \
    do {                                                                     \
        ushort* _d = &lds[((((t) & 1) * 2 + 1) * 2 + (h)) * 8192];           \
        const long _o = (long)(h) * 128 * ldb + (long)(t) * 64;              \
        gload16(bS0 + _o, _d + tid * 8);                                     \
        gload16(bS1 + _o, _d + (tid + 512) * 8);                             \
    } while (0)
#define GEMM_LDA(MB)                                                         \
    _Pragma("unroll") for (int mi = 0; mi < 4; ++mi)                         \
    _Pragma("unroll") for (int ks = 0; ks < 2; ++ks)                         \
        a[mi][ks] = __builtin_bit_cast(                                      \
            bf16x8, *(const short8*)&ldsA[((MB) + mi) * 1024 + ks * 512 + aoff]);
#define GEMM_LDB(NB)                                                         \
    _Pragma("unroll") for (int ni = 0; ni < 2; ++ni)                         \
    _Pragma("unroll") for (int ks = 0; ks < 2; ++ks)                         \
        b[(NB) + ni][ks] = __builtin_bit_cast(                               \
            bf16x8, *(const short8*)&ldsB[((NB) + ni) * 1024 + ks * 512 + boff]);
#define GEMM_MFMA(MB, NB)                                                    \
    __builtin_amdgcn_s_setprio(1);                                           \
    _Pragma("unroll") for (int mi = 0; mi < 4; ++mi)                         \
    _Pragma("unroll") for (int ni = 0; ni < 2; ++ni)                         \
    _Pragma("unroll") for (int ks = 0; ks < 2; ++ks)                         \
        acc[(MB) + mi][(NB) + ni] = __builtin_amdgcn_mfma_f32_16x16x32_bf16( \
            a[mi][ks], b[(NB) + ni][ks], acc[(MB) + mi][(NB) + ni], 0, 0, 0);\
    __builtin_amdgcn_s_setprio(0);

template <int EPI>
__global__ __launch_bounds__(512, 2) void gemm256(
    const ushort* __restrict__ A, const ushort* __restrict__ Bt,
    int K, int lda, int ldb, int ldc,
    float* __restrict__ outF, ushort* __restrict__ outB,
    const float* __restrict__ add0, const ushort* __restrict__ mul0) {
    extern __shared__ ushort lds[];

    const int tid  = threadIdx.x;
    const int lane = tid & 63;
    const int quad = lane >> 4;
    const int l16  = lane & 15;
    const int wv   = tid >> 6;      // 0..7
    const int wmi  = wv >> 2;       // 0..1 -> rows wmi*128 (A half = wmi)
    const int wni  = wv & 3;        // 0..3 -> cols wni*64  (B half = wni>>1)

    // XCD-chunked bijective swizzle, column-major tile order:
    // each XCD chunk = contiguous y-range within one x (one B panel).
    const int gx  = gridDim.x;
    const int gy  = gridDim.y;
    const int nwg = gx * gy;
    int b_ = blockIdx.y * gx + blockIdx.x;
    b_ = (b_ & 7) * (nwg >> 3) + (b_ >> 3);
    const long m0 = (long)(b_ % gy) * 256;
    const long n0 = (long)(b_ / gy) * 256;

    floatx4 acc[8][4];
#pragma unroll
    for (int i = 0; i < 8; ++i)
#pragma unroll
        for (int j = 0; j < 4; ++j) acc[i][j] = (floatx4)0.f;

    // staging slot decode: slot j (16B) -> rowInHalf, col (fragment order)
    const int j1 = tid + 512;
    const int r0 = ((tid >> 7) << 4) + (tid & 15);
    const int c0 = (tid >> 4) & 7;
    const int col0 = (c0 & 3) * 8 + (c0 >> 2) * 32;
    const int r1 = ((j1 >> 7) << 4) + (j1 & 15);
    const int c1 = (j1 >> 4) & 7;
    const int col1 = (c1 & 3) * 8 + (c1 >> 2) * 32;
    const ushort* aS0 = A + (m0 + r0) * (long)lda + col0;
    const ushort* aS1 = A + (m0 + r1) * (long)lda + col1;
    const ushort* bS0 = Bt + (n0 + r0) * (long)ldb + col0;
    const ushort* bS1 = Bt + (n0 + r1) * (long)ldb + col1;

    const int aoff = quad * 128 + l16 * 8;                      // ushort units
    const int boff = (wni & 1) * 4096 + quad * 128 + l16 * 8;

    const int NT = K >> 6;

    // prologue: tile0 {A0,A1,B0,B1} + tile1 {B0,B1}; keep last 2 halves in flight
    STAGE_A(0, 0); STAGE_A(1, 0);
    STAGE_B(0, 0); STAGE_B(1, 0);
    if (NT > 1) { STAGE_B(0, 1); STAGE_B(1, 1); WAIT_VM4; }
    else        { WAIT_VM0; }
    SBAR;

    bf16x8 a[4][2], b[4][2];
    for (int kt = 0; kt < NT; ++kt) {
        const int d = kt & 1;
        const ushort* ldsA = &lds[((d * 2 + 0) * 2 + wmi) * 8192];
        const ushort* ldsB = &lds[((d * 2 + 1) * 2 + (wni >> 1)) * 8192];

        // P1: read a0-3 + b0-1 ; stage A0(kt+1) ; MFMA m0-3 x n0-1
        GEMM_LDA(0)
        GEMM_LDB(0)
        if (kt + 1 < NT) STAGE_A(0, kt + 1);
        SBAR; WAIT_LGKM0; SCHED0;
        GEMM_MFMA(0, 0)
        SCHED0; SBAR;

        // P2: read b2-3 ; stage A1(kt+1) ; MFMA m0-3 x n2-3
        GEMM_LDB(2)
        if (kt + 1 < NT) STAGE_A(1, kt + 1);
        SBAR; WAIT_LGKM0; SCHED0;
        GEMM_MFMA(0, 2)
        SCHED0; SBAR;

        // P3: read a4-7 (reuse a regs) ; stage B0(kt+2) ; MFMA m4-7 x n2-3
        GEMM_LDA(4)
        if (kt + 2 < NT) STAGE_B(0, kt + 2);
        SBAR; WAIT_LGKM0; SCHED0;
        GEMM_MFMA(4, 2)
        SCHED0; SBAR;

        // P4: stage B1(kt+2) ; counted vmcnt (drain only at the tail) ; MFMA m4-7 x n0-1
        if (kt + 2 < NT) STAGE_B(1, kt + 2);
        if (kt < NT - 2) { WAIT_VM4; } else { WAIT_VM0; }
        SBAR; SCHED0;
        GEMM_MFMA(4, 0)
        SCHED0; SBAR;
    }

    // C/D layout: col = lane&15, row = quad*4 + reg (m89/m91-verified)
#pragma unroll
    for (int mi = 0; mi < 8; ++mi) {
#pragma unroll
        for (int ni = 0; ni < 4; ++ni) {
            const long n = n0 + wni * 64 + ni * 16 + l16;
#pragma unroll
            for (int r = 0; r < 4; ++r) {
                const long m = m0 + wmi * 128 + mi * 16 + quad * 4 + r;
                const long idx = m * (long)ldc + n;
                float v = acc[mi][ni][r];
                if constexpr (EPI == 0) {
                    outB[idx] = f2bf(v);
                } else if constexpr (EPI == 1) {
                    outB[idx] = f2bf(1.f / (1.f + __expf(-v)));
                } else if constexpr (EPI == 2) {
                    float t = fmaxf(v, 0.f);
                    outB[idx] = f2bf(t * t);
                } else if constexpr (EPI == 3) {
                    outF[idx] = add0[idx] + bf2f(mul0[idx]) * v;
                }
            }
        }
    }
}

// ---------------------------------------------------------------------------
// Fused LayerNorm + time-shift + mix -> bf16 outputs (3 mixes), f32 input.
// ---------------------------------------------------------------------------
__global__ __launch_bounds__(256) void ln_mix3(
    const float* __restrict__ x, const float* __restrict__ g,
    const float* __restrict__ be,
    const float* __restrict__ mx0, const float* __restrict__ mx1,
    const float* __restrict__ mx2,
    ushort* __restrict__ o0, ushort* __restrict__ o1, ushort* __restrict__ o2,
    int T, int C) {
    const long row = blockIdx.x;
    const int t = (int)(row % T);
    const int tid = threadIdx.x;
    const int i0 = tid * 4;

    floatx4 xc = *(const floatx4*)&x[row * C + i0];
    floatx4 xp = (floatx4)0.f;
    if (t > 0) xp = *(const floatx4*)&x[(row - 1) * C + i0];

    float sc = xc.x + xc.y + xc.z + xc.w;
    float qc = xc.x * xc.x + xc.y * xc.y + xc.z * xc.z + xc.w * xc.w;
    float sp = xp.x + xp.y + xp.z + xp.w;
    float qp = xp.x * xp.x + xp.y * xp.y + xp.z * xp.z + xp.w * xp.w;

#pragma unroll
    for (int off = 32; off; off >>= 1) {
        sc += __shfl_xor(sc, off);
        qc += __shfl_xor(qc, off);
        sp += __shfl_xor(sp, off);
        qp += __shfl_xor(qp, off);
    }
    __shared__ float part[4][4];
    const int wv = tid >> 6;
    if ((tid & 63) == 0) {
        part[wv][0] = sc; part[wv][1] = qc; part[wv][2] = sp; part[wv][3] = qp;
    }
    __syncthreads();
    sc = part[0][0] + part[1][0] + part[2][0] + part[3][0];
    qc = part[0][1] + part[1][1] + part[2][1] + part[3][1];
    sp = part[0][2] + part[1][2] + part[2][2] + part[3][2];
    qp = part[0][3] + part[1][3] + part[2][3] + part[3][3];

    const float invC = 1.f / (float)C;
    float muc = sc * invC;
    float rsc = rsqrtf(qc * invC - muc * muc + LN_EPS);
    float mup = sp * invC;
    float rsp = rsqrtf(qp * invC - mup * mup + LN_EPS);

    floatx4 gv = *(const floatx4*)&g[i0];
    floatx4 bv = *(const floatx4*)&be[i0];
    floatx4 hc = (xc - muc) * rsc * gv + bv;
    floatx4 hp = (floatx4)0.f;
    if (t > 0) hp = (xp - mup) * rsp * gv + bv;

    {
        floatx4 mk = *(const floatx4*)&mx0[i0];
        floatx4 v = hc * mk + hp * (1.f - mk);
        ushort4 pk;
        pk.x = f2bf(v.x); pk.y = f2bf(v.y); pk.z = f2bf(v.z); pk.w = f2bf(v.w);
        *(ushort4*)&o0[row * C + i0] = pk;
    }
    {
        floatx4 mk = *(const floatx4*)&mx1[i0];
        floatx4 v = hc * mk + hp * (1.f - mk);
        ushort4 pk;
        pk.x = f2bf(v.x); pk.y = f2bf(v.y); pk.z = f2bf(v.z); pk.w = f2bf(v.w);
        *(ushort4*)&o1[row * C + i0] = pk;
    }
    {
        floatx4 mk = *(const floatx4*)&mx2[i0];
        floatx4 v = hc * mk + hp * (1.f - mk);
        ushort4 pk;
        pk.x = f2bf(v.x); pk.y = f2bf(v.y); pk.z = f2bf(v.z); pk.w = f2bf(v.w);
        *(ushort4*)&o2[row * C + i0] = pk;
    }
}

// ---------------------------------------------------------------------------
// Fused: out = x + ry (residual), then LayerNorm(out) + shift + 2 mixes.
// ---------------------------------------------------------------------------
__global__ __launch_bounds__(256) void ln_mix_add(
    const float* __restrict__ x, const ushort* __restrict__ ry,
    const float* __restrict__ g, const float* __restrict__ be,
    const float* __restrict__ mx0, const float* __restrict__ mx1,
    float* __restrict__ outx,
    ushort* __restrict__ o0, ushort* __restrict__ o1, int T, int C) {
    const long row = blockIdx.x;
    const int t = (int)(row % T);
    const int tid = threadIdx.x;
    const int i0 = tid * 4;

    floatx4 xc = *(const floatx4*)&x[row * C + i0];
    ushort4 rc = *(const ushort4*)&ry[row * C + i0];
    xc.x += bf2f(rc.x); xc.y += bf2f(rc.y); xc.z += bf2f(rc.z); xc.w += bf2f(rc.w);
    *(floatx4*)&outx[row * C + i0] = xc;

    floatx4 xp = (floatx4)0.f;
    if (t > 0) {
        xp = *(const floatx4*)&x[(row - 1) * C + i0];
        ushort4 rp = *(const ushort4*)&ry[(row - 1) * C + i0];
        xp.x += bf2f(rp.x); xp.y += bf2f(rp.y); xp.z += bf2f(rp.z); xp.w += bf2f(rp.w);
    }

    float sc = xc.x + xc.y + xc.z + xc.w;
    float qc = xc.x * xc.x + xc.y * xc.y + xc.z * xc.z + xc.w * xc.w;
    float sp = xp.x + xp.y + xp.z + xp.w;
    float qp = xp.x * xp.x + xp.y * xp.y + xp.z * xp.z + xp.w * xp.w;

#pragma unroll
    for (int off = 32; off; off >>= 1) {
        sc += __shfl_xor(sc, off);
        qc += __shfl_xor(qc, off);
        sp += __shfl_xor(sp, off);
        qp += __shfl_xor(qp, off);
    }
    __shared__ float part[4][4];
    const int wv = tid >> 6;
    if ((tid & 63) == 0) {
        part[wv][0] = sc; part[wv][1] = qc; part[wv][2] = sp; part[wv][3] = qp;
    }
    __syncthreads();
    sc = part[0][0] + part[1][0] + part[2][0] + part[3][0];
    qc = part[0][1] + part[1][1] + part[2][1] + part[3][1];
    sp = part[0][2] + part[1][2] + part[2][2] + part[3][2];
    qp = part[0][3] + part[1][3] + part[2][3] + part[3][3];

    const float invC = 1.f / (float)C;
    float muc = sc * invC;
    float rsc = rsqrtf(qc * invC - muc * muc + LN_EPS);
    float mup = sp * invC;
    float rsp = rsqrtf(qp * invC - mup * mup + LN_EPS);

    floatx4 gv = *(const floatx4*)&g[i0];
    floatx4 bv = *(const floatx4*)&be[i0];
    floatx4 hc = (xc - muc) * rsc * gv + bv;
    floatx4 hp = (floatx4)0.f;
    if (t > 0) hp = (xp - mup) * rsp * gv + bv;

    {
        floatx4 mk = *(const floatx4*)&mx0[i0];
        floatx4 v = hc * mk + hp * (1.f - mk);
        ushort4 pk;
        pk.x = f2bf(v.x); pk.y = f2bf(v.y); pk.z = f2bf(v.z); pk.w = f2bf(v.w);
        *(ushort4*)&o0[row * C + i0] = pk;
    }
    {
        floatx4 mk = *(const floatx4*)&mx1[i0];
        floatx4 v = hc * mk + hp * (1.f - mk);
        ushort4 pk;
        pk.x = f2bf(v.x); pk.y = f2bf(v.y); pk.z = f2bf(v.z); pk.w = f2bf(v.w);
        *(ushort4*)&o1[row * C + i0] = pk;
    }
}

// ===========================================================================
// Segmented exact WKV scan. T split into SEG segments of L steps.
// ===========================================================================

// K1: per-segment pp from zero state (reads k only)
__global__ __launch_bounds__(256) void wkv_pp_local(
    const float* __restrict__ w, const ushort* __restrict__ k,
    float* __restrict__ pp_loc, int C, int L) {
    const int g = blockIdx.x * 256 + threadIdx.x;
    const int c = g % C;
    const long seg = g / C;
    const float L2E = 1.4426950408889634f;
    const float w2 = w[c] * L2E;
    const ushort* kp = k + seg * L * C + c;
    float pp = -1e38f;
    for (int j = 0; j < L; ++j) {
        float kk = bf2f(kp[(long)j * C]) * L2E;
        float ppw = pp + w2;
        float wk = w2 + kk;
        float p2 = fmaxf(ppw, wk);
        pp = p2 + log2f(exp2f(ppw - p2) + exp2f(wk - p2));
    }
    pp_loc[g] = pp;
}

// K2: sequential pp composition per channel
__global__ __launch_bounds__(256) void wkv_pp_compose(
    const float* __restrict__ w, const float* __restrict__ pp_loc,
    float* __restrict__ pp_in, int C, int SEG, int L) {
    const int g = blockIdx.x * 256 + threadIdx.x;  // b*C + c
    const int c = g % C;
    const long b = g / C;
    const float wL = w[c] * 1.4426950408889634f * (float)L;
    float pp = -1e38f;
    for (int s = 0; s < SEG; ++s) {
        const long idx = (b * SEG + s) * C + c;
        pp_in[idx] = pp;
        float lhs = pp + wL;
        float rhs = pp_loc[idx];
        float m = fmaxf(lhs, rhs);
        pp = m + log2f(exp2f(lhs - m) + exp2f(rhs - m));
    }
}

// K3: per-segment (alpha,beta) on the TRUE pp path
__global__ __launch_bounds__(256) void wkv_ab_local(
    const float* __restrict__ w, const ushort* __restrict__ k,
    const ushort* __restrict__ v, const float* __restrict__ pp_in,
    float* __restrict__ alpha, float* __restrict__ beta, int C, int L) {
    const int g = blockIdx.x * 256 + threadIdx.x;
    const int c = g % C;
    const long seg = g / C;
    const float L2E = 1.4426950408889634f;
    const float w2 = w[c] * L2E;
    const ushort* kp = k + seg * L * C + c;
    const ushort* vp = v + seg * L * C + c;
    float pp = pp_in[g];
    float al = 1.f, be = 0.f;
    for (int j = 0; j < L; ++j) {
        float kk = bf2f(kp[(long)j * C]) * L2E;
        float vv = bf2f(vp[(long)j * C]);
        float ppw = pp + w2;
        float wk = w2 + kk;
        float p2 = fmaxf(ppw, wk);
        float e1u = exp2f(ppw - p2);
        float e2u = exp2f(wk - p2);
        al *= e1u;
        be = e1u * be + e2u * vv;
        pp = p2 + log2f(e1u + e2u);
    }
    alpha[g] = al;
    beta[g] = be;
}

// K4: sequential aa composition per channel
__global__ __launch_bounds__(256) void wkv_aa_compose(
    const float* __restrict__ alpha, const float* __restrict__ beta,
    float* __restrict__ aa_in, int C, int SEG) {
    const int g = blockIdx.x * 256 + threadIdx.x;  // b*C + c
    const int c = g % C;
    const long b = g / C;
    float aa = 0.f;
    for (int s = 0; s < SEG; ++s) {
        const long idx = (b * SEG + s) * C + c;
        aa_in[idx] = aa;
        aa = alpha[idx] * aa + beta[idx];
    }
    (void)c;
}

// K5: per-segment emit with true incoming state: ry = r * y, [M][C] layout
__global__ __launch_bounds__(256) void wkv_emit(
    const float* __restrict__ w, const float* __restrict__ u,
    const ushort* __restrict__ k, const ushort* __restrict__ v,
    const ushort* __restrict__ r, const float* __restrict__ aa_in,
    const float* __restrict__ pp_in, ushort* __restrict__ ry, int C, int L) {
    const int g = blockIdx.x * 256 + threadIdx.x;
    const int c = g % C;
    const long seg = g / C;
    const float L2E = 1.4426950408889634f;
    const float w2 = w[c] * L2E;
    const float u2 = u[c] * L2E;
    const long base = seg * L * C + c;
    const ushort* kp = k + base;
    const ushort* vp = v + base;
    const ushort* rp = r + base;
    ushort* op = ry + base;
    float aa = aa_in[g];
    float pp = pp_in[g];
    for (int j = 0; j < L; ++j) {
        const long o = (long)j * C;
        float kk = bf2f(kp[o]) * L2E;
        float vv = bf2f(vp[o]);
        float uk = u2 + kk;
        float p = fmaxf(pp, uk);
        float e1 = exp2f(pp - p);
        float e2 = exp2f(uk - p);
        float y = __fdividef(e1 * aa + e2 * vv, e1 + e2);
        op[o] = f2bf(bf2f(rp[o]) * y);
        float ppw = pp + w2;
        float wk = w2 + kk;
        float p2 = fmaxf(ppw, wk);
        float e1u = exp2f(ppw - p2);
        float e2u = exp2f(wk - p2);
        aa = e1u * aa + e2u * vv;
        pp = p2 + log2f(e1u + e2u);
    }
}

// out[n][k] = bf16(in[k][n]); in is [K][N] fp32 row-major. block (32,8).
__global__ __launch_bounds__(256) void transpose_bf16(
    const float* __restrict__ in, ushort* __restrict__ out, int K, int N) {
    __shared__ float tile[32][33];
    const int tx = threadIdx.x, ty = threadIdx.y;
    const long k0 = (long)blockIdx.y * 32, n0 = (long)blockIdx.x * 32;
#pragma unroll
    for (int i = 0; i < 4; i++)
        tile[ty + i * 8][tx] = in[(k0 + ty + i * 8) * N + n0 + tx];
    __syncthreads();
#pragma unroll
    for (int i = 0; i < 4; i++)
        out[(n0 + ty + i * 8) * K + k0 + tx] = f2bf(tile[tx][ty + i * 8]);
}

extern "C" void kernel_launch(void* const* d_in, const int* in_sizes, int n_in,
                              void* d_out, int out_size, void* d_ws, size_t ws_size,
                              hipStream_t stream) {
    const float* x      = (const float*)d_in[0];
    const float* tdecay = (const float*)d_in[1];
    const float* tfirst = (const float*)d_in[2];
    const float* w_tk   = (const float*)d_in[3];
    const float* w_tv   = (const float*)d_in[4];
    const float* w_tr   = (const float*)d_in[5];
    const float* w_ck   = (const float*)d_in[6];
    const float* w_cv   = (const float*)d_in[7];
    const float* w_cr   = (const float*)d_in[8];
    const float* ln1g   = (const float*)d_in[9];
    const float* ln1b   = (const float*)d_in[10];
    const float* ln2g   = (const float*)d_in[11];
    const float* ln2b   = (const float*)d_in[12];
    const float* mixk   = (const float*)d_in[13];
    const float* mixv   = (const float*)d_in[14];
    const float* mixr   = (const float*)d_in[15];
    const float* cmixk  = (const float*)d_in[16];
    const float* cmixr  = (const float*)d_in[17];
    float* out = (float*)d_out;

    const int C  = in_sizes[1];              // 1024
    const long M = (long)in_sizes[0] / C;    // 16384
    const int T  = 2048;
    const int B  = (int)(M / T);
    const int H  = 2 * C;                    // 2048 = half of 4C
    const int SEG = 64;                      // segments per sequence
    const int L  = T / SEG;                  // 32 steps per segment
    const int NSEG = B * SEG;                // 512 total segments

    // one-time: allow 128 KiB dynamic LDS for gemm256
    static bool s_attr = []() {
        (void)hipFuncSetAttribute((const void*)gemm256<0>,
                                  hipFuncAttributeMaxDynamicSharedMemorySize, 131072);
        (void)hipFuncSetAttribute((const void*)gemm256<1>,
                                  hipFuncAttributeMaxDynamicSharedMemorySize, 131072);
        (void)hipFuncSetAttribute((const void*)gemm256<2>,
                                  hipFuncAttributeMaxDynamicSharedMemorySize, 131072);
        (void)hipFuncSetAttribute((const void*)gemm256<3>,
                                  hipFuncAttributeMaxDynamicSharedMemorySize, 131072);
        return true;
    }();
    (void)s_attr;
    const int SMEM = 131072;

    // workspace layout identical to previous (verified) version
    const size_t MBy = 1024ull * 1024ull;
    char* w8 = (char*)d_ws;
    ushort* wT_tk  = (ushort*)(w8 + 0 * MBy);
    ushort* wT_tv  = (ushort*)(w8 + 2 * MBy);
    ushort* wT_tr  = (ushort*)(w8 + 4 * MBy);
    ushort* wT_cr  = (ushort*)(w8 + 6 * MBy);
    ushort* wT_ck  = (ushort*)(w8 + 8 * MBy);
    ushort* wT_cv0 = (ushort*)(w8 + 16 * MBy);
    ushort* wT_cv1 = (ushort*)(w8 + 20 * MBy);
    ushort* xk     = (ushort*)(w8 + 24 * MBy);
    ushort* xv     = (ushort*)(w8 + 56 * MBy);
    ushort* xr     = (ushort*)(w8 + 88 * MBy);
    ushort* kbuf   = (ushort*)(w8 + 120 * MBy);
    ushort* vbuf   = (ushort*)(w8 + 152 * MBy);
    ushort* rbuf   = (ushort*)(w8 + 24 * MBy);   // xk dead
    float*  pp_loc = (float*)(w8 + 56 * MBy);    // xv dead (2MB each)
    float*  pp_in  = (float*)(w8 + 58 * MBy);
    float*  alpha  = (float*)(w8 + 60 * MBy);
    float*  beta   = (float*)(w8 + 62 * MBy);
    float*  aa_in  = (float*)(w8 + 64 * MBy);
    ushort* ry     = (ushort*)(w8 + 88 * MBy);   // xr dead
    ushort* ck     = (ushort*)(w8 + 120 * MBy);  // kbuf dead
    ushort* cr     = (ushort*)(w8 + 152 * MBy);  // vbuf dead
    ushort* scr    = (ushort*)(w8 + 24 * MBy);   // rbuf dead
    ushort* kkbuf  = (ushort*)(w8 + 56 * MBy);   // states/ry dead, 64MB

    dim3 tb(32, 8);
    transpose_bf16<<<dim3(C / 32, C / 32), tb, 0, stream>>>(w_tk, wT_tk, C, C);
    transpose_bf16<<<dim3(C / 32, C / 32), tb, 0, stream>>>(w_tv, wT_tv, C, C);
    transpose_bf16<<<dim3(C / 32, C / 32), tb, 0, stream>>>(w_tr, wT_tr, C, C);
    transpose_bf16<<<dim3(C / 32, C / 32), tb, 0, stream>>>(w_cr, wT_cr, C, C);
    transpose_bf16<<<dim3(4 * C / 32, C / 32), tb, 0, stream>>>(w_ck, wT_ck, C, 4 * C);
    transpose_bf16<<<dim3(C / 32, H / 32), tb, 0, stream>>>(w_cv, wT_cv0, H, C);
    transpose_bf16<<<dim3(C / 32, H / 32), tb, 0, stream>>>(w_cv + (long)H * C, wT_cv1, H, C);

    ln_mix3<<<(int)M, 256, 0, stream>>>(x, ln1g, ln1b, mixk, mixv, mixr,
                                        xk, xv, xr, T, C);

    dim3 g256(C / 256, (int)(M / 256));
    gemm256<0><<<g256, 512, SMEM, stream>>>(xk, wT_tk, C, C, C, C,
                                            nullptr, kbuf, nullptr, nullptr);
    gemm256<0><<<g256, 512, SMEM, stream>>>(xv, wT_tv, C, C, C, C,
                                            nullptr, vbuf, nullptr, nullptr);
    gemm256<1><<<g256, 512, SMEM, stream>>>(xr, wT_tr, C, C, C, C,
                                            nullptr, rbuf, nullptr, nullptr);

    // segmented exact WKV scan
    const int segthreads = NSEG * C;                     // 524288
    wkv_pp_local<<<segthreads / 256, 256, 0, stream>>>(tdecay, kbuf, pp_loc, C, L);
    wkv_pp_compose<<<(B * C) / 256, 256, 0, stream>>>(tdecay, pp_loc, pp_in, C, SEG, L);
    wkv_ab_local<<<segthreads / 256, 256, 0, stream>>>(tdecay, kbuf, vbuf, pp_in,
                                                       alpha, beta, C, L);
    wkv_aa_compose<<<(B * C) / 256, 256, 0, stream>>>(alpha, beta, aa_in, C, SEG);
    wkv_emit<<<segthreads / 256, 256, 0, stream>>>(tdecay, tfirst, kbuf, vbuf, rbuf,
                                                   aa_in, pp_in, ry, C, L);

    // fused: out = x + ry, then LN2 + shift + channel mixes
    ln_mix_add<<<(int)M, 256, 0, stream>>>(x, ry, ln2g, ln2b, cmixk, cmixr,
                                           out, ck, cr, T, C);

    gemm256<1><<<g256, 512, SMEM, stream>>>(cr, wT_cr, C, C, C, C,
                                            nullptr, scr, nullptr, nullptr);

    // channel-mix hidden (4C) processed in two 2C halves through one 64MB buffer
    for (int h = 0; h < 2; ++h) {
        const ushort* wck_h = wT_ck + (long)h * H * C;
        const ushort* wcv_h = (h == 0) ? wT_cv0 : wT_cv1;
        gemm256<2><<<dim3(H / 256, (int)(M / 256)), 512, SMEM, stream>>>(
            ck, wck_h, C, C, C, H, nullptr, kkbuf, nullptr, nullptr);
        gemm256<3><<<g256, 512, SMEM, stream>>>(
            kkbuf, wcv_h, H, H, H, C, out, nullptr, out, scr);
    }
}

// Round 9
// 882.330 us; speedup vs baseline: 1.3081x; 1.0202x over previous
//
#include <hip/hip_runtime.h>
#include <hip/hip_bf16.h>
#include <stdint.h>

#define LN_EPS 1e-5f
#define LNR 8

typedef __attribute__((ext_vector_type(8))) __bf16 bf16x8;
typedef __attribute__((ext_vector_type(8))) short short8;
typedef __attribute__((ext_vector_type(4))) float floatx4;

__device__ __forceinline__ ushort f2bf(float f) {
    __hip_bfloat16 h = __float2bfloat16(f);
    return *reinterpret_cast<ushort*>(&h);
}
__device__ __forceinline__ float bf2f(ushort u) {
    return __builtin_bit_cast(float, ((unsigned int)u) << 16);
}

// async global->LDS, 16B per lane; LDS dest = wave-uniform base + lane*16
__device__ __forceinline__ void gload16(const void* g, void* l) {
#if __has_builtin(__builtin_amdgcn_global_load_lds)
    __builtin_amdgcn_global_load_lds(
        (const __attribute__((address_space(1))) unsigned int*)g,
        (__attribute__((address_space(3))) unsigned int*)l, 16, 0, 0);
#else
    *(int4*)l = *(const int4*)g;
#endif
}

#define SBAR __builtin_amdgcn_s_barrier()
#define SCHED0 __builtin_amdgcn_sched_barrier(0)
#define WAIT_LGKM0 asm volatile("s_waitcnt lgkmcnt(0)" ::: "memory")
#define WAIT_VM4 asm volatile("s_waitcnt vmcnt(4)" ::: "memory")
#define WAIT_VM0 asm volatile("s_waitcnt vmcnt(0)" ::: "memory")

// ---------------------------------------------------------------------------
// GEMM: C[M,N] = A[M,K](bf16 rm, lda) x Bt[N,K](bf16 rm, ldb)  (Bt = B^T)
// 256x256 tile, BK=64, 512 thr (8 waves 2Mx4N, each 128x64 out), 8-phase
// schedule with counted vmcnt (T3+T4), conflict-free fragment-order LDS,
// setprio around MFMA clusters (T5). 128 KiB dynamic LDS, 1 block/CU.
// VERIFIED at 900 us total (rounds 1 & 7) — structure frozen this round.
// EPI: 0 bf16 | 1 bf16 sigmoid | 2 bf16 relu^2 | 3 f32 out=add0+mul0*acc
// ---------------------------------------------------------------------------
#define STAGE_A(h, t)                                                        \
    do {                                                                     \
        ushort* _d = &lds[((((t) & 1) * 2 + 0) * 2 + (h)) * 8192];           \
        const long _o = (long)(h) * 128 * lda + (long)(t) * 64;              \
        gload16(aS0 + _o, _d + tid * 8);                                     \
        gload16(aS1 + _o, _d + (tid + 512) * 8);                             \
    } while (0)
#define STAGE_B(h, t)                                                        \
    do {                                                                     \
        ushort* _d = &lds[((((t) & 1) * 2 + 1) * 2 + (h)) * 8192];           \
        const long _o = (long)(h) * 128 * ldb + (long)(t) * 64;              \
        gload16(bS0 + _o, _d + tid * 8);                                     \
        gload16(bS1 + _o, _d + (tid + 512) * 8);                             \
    } while (0)
#define GEMM_LDA(MB)                                                         \
    _Pragma("unroll") for (int mi = 0; mi < 4; ++mi)                         \
    _Pragma("unroll") for (int ks = 0; ks < 2; ++ks)                         \
        a[mi][ks] = __builtin_bit_cast(                                      \
            bf16x8, *(const short8*)&ldsA[((MB) + mi) * 1024 + ks * 512 + aoff]);
#define GEMM_LDB(NB)                                                         \
    _Pragma("unroll") for (int ni = 0; ni < 2; ++ni)                         \
    _Pragma("unroll") for (int ks = 0; ks < 2; ++ks)                         \
        b[(NB) + ni][ks] = __builtin_bit_cast(                               \
            bf16x8, *(const short8*)&ldsB[((NB) + ni) * 1024 + ks * 512 + boff]);
#define GEMM_MFMA(MB, NB)                                                    \
    __builtin_amdgcn_s_setprio(1);                                           \
    _Pragma("unroll") for (int mi = 0; mi < 4; ++mi)                         \
    _Pragma("unroll") for (int ni = 0; ni < 2; ++ni)                         \
    _Pragma("unroll") for (int ks = 0; ks < 2; ++ks)                         \
        acc[(MB) + mi][(NB) + ni] = __builtin_amdgcn_mfma_f32_16x16x32_bf16( \
            a[mi][ks], b[(NB) + ni][ks], acc[(MB) + mi][(NB) + ni], 0, 0, 0);\
    __builtin_amdgcn_s_setprio(0);

template <int EPI>
__global__ __launch_bounds__(512, 2) void gemm256(
    const ushort* __restrict__ A, const ushort* __restrict__ Bt,
    int K, int lda, int ldb, int ldc,
    float* __restrict__ outF, ushort* __restrict__ outB,
    const float* __restrict__ add0, const ushort* __restrict__ mul0) {
    extern __shared__ ushort lds[];

    const int tid  = threadIdx.x;
    const int lane = tid & 63;
    const int quad = lane >> 4;
    const int l16  = lane & 15;
    const int wv   = tid >> 6;      // 0..7
    const int wmi  = wv >> 2;       // 0..1 -> rows wmi*128 (A half = wmi)
    const int wni  = wv & 3;        // 0..3 -> cols wni*64  (B half = wni>>1)

    // XCD-chunked bijective swizzle, column-major tile order (measured: null
    // vs row-major but kept — it is the measured 900us configuration).
    const int gx  = gridDim.x;
    const int gy  = gridDim.y;
    const int nwg = gx * gy;
    int b_ = blockIdx.y * gx + blockIdx.x;
    b_ = (b_ & 7) * (nwg >> 3) + (b_ >> 3);
    const long m0 = (long)(b_ % gy) * 256;
    const long n0 = (long)(b_ / gy) * 256;

    floatx4 acc[8][4];
#pragma unroll
    for (int i = 0; i < 8; ++i)
#pragma unroll
        for (int j = 0; j < 4; ++j) acc[i][j] = (floatx4)0.f;

    // staging slot decode: slot j (16B) -> rowInHalf, col (fragment order)
    const int j1 = tid + 512;
    const int r0 = ((tid >> 7) << 4) + (tid & 15);
    const int c0 = (tid >> 4) & 7;
    const int col0 = (c0 & 3) * 8 + (c0 >> 2) * 32;
    const int r1 = ((j1 >> 7) << 4) + (j1 & 15);
    const int c1 = (j1 >> 4) & 7;
    const int col1 = (c1 & 3) * 8 + (c1 >> 2) * 32;
    const ushort* aS0 = A + (m0 + r0) * (long)lda + col0;
    const ushort* aS1 = A + (m0 + r1) * (long)lda + col1;
    const ushort* bS0 = Bt + (n0 + r0) * (long)ldb + col0;
    const ushort* bS1 = Bt + (n0 + r1) * (long)ldb + col1;

    const int aoff = quad * 128 + l16 * 8;                      // ushort units
    const int boff = (wni & 1) * 4096 + quad * 128 + l16 * 8;

    const int NT = K >> 6;

    // prologue: tile0 {A0,A1,B0,B1} + tile1 {B0,B1}; keep last 2 halves in flight
    STAGE_A(0, 0); STAGE_A(1, 0);
    STAGE_B(0, 0); STAGE_B(1, 0);
    if (NT > 1) { STAGE_B(0, 1); STAGE_B(1, 1); WAIT_VM4; }
    else        { WAIT_VM0; }
    SBAR;

    bf16x8 a[4][2], b[4][2];
    for (int kt = 0; kt < NT; ++kt) {
        const int d = kt & 1;
        const ushort* ldsA = &lds[((d * 2 + 0) * 2 + wmi) * 8192];
        const ushort* ldsB = &lds[((d * 2 + 1) * 2 + (wni >> 1)) * 8192];

        // P1: read a0-3 + b0-1 ; stage A0(kt+1) ; MFMA m0-3 x n0-1
        GEMM_LDA(0)
        GEMM_LDB(0)
        if (kt + 1 < NT) STAGE_A(0, kt + 1);
        SBAR; WAIT_LGKM0; SCHED0;
        GEMM_MFMA(0, 0)
        SCHED0; SBAR;

        // P2: read b2-3 ; stage A1(kt+1) ; MFMA m0-3 x n2-3
        GEMM_LDB(2)
        if (kt + 1 < NT) STAGE_A(1, kt + 1);
        SBAR; WAIT_LGKM0; SCHED0;
        GEMM_MFMA(0, 2)
        SCHED0; SBAR;

        // P3: read a4-7 (reuse a regs) ; stage B0(kt+2) ; MFMA m4-7 x n2-3
        GEMM_LDA(4)
        if (kt + 2 < NT) STAGE_B(0, kt + 2);
        SBAR; WAIT_LGKM0; SCHED0;
        GEMM_MFMA(4, 2)
        SCHED0; SBAR;

        // P4: stage B1(kt+2) ; counted vmcnt (drain only at the tail) ; MFMA m4-7 x n0-1
        if (kt + 2 < NT) STAGE_B(1, kt + 2);
        if (kt < NT - 2) { WAIT_VM4; } else { WAIT_VM0; }
        SBAR; SCHED0;
        GEMM_MFMA(4, 0)
        SCHED0; SBAR;
    }

    // C/D layout: col = lane&15, row = quad*4 + reg (m89/m91-verified)
#pragma unroll
    for (int mi = 0; mi < 8; ++mi) {
#pragma unroll
        for (int ni = 0; ni < 4; ++ni) {
            const long n = n0 + wni * 64 + ni * 16 + l16;
#pragma unroll
            for (int r = 0; r < 4; ++r) {
                const long m = m0 + wmi * 128 + mi * 16 + quad * 4 + r;
                const long idx = m * (long)ldc + n;
                float v = acc[mi][ni][r];
                if constexpr (EPI == 0) {
                    outB[idx] = f2bf(v);
                } else if constexpr (EPI == 1) {
                    outB[idx] = f2bf(1.f / (1.f + __expf(-v)));
                } else if constexpr (EPI == 2) {
                    float t = fmaxf(v, 0.f);
                    outB[idx] = f2bf(t * t);
                } else if constexpr (EPI == 3) {
                    outF[idx] = add0[idx] + bf2f(mul0[idx]) * v;
                }
            }
        }
    }
}

// ---------------------------------------------------------------------------
// Row-batched LayerNorm + time-shift + mix (3 outputs). LNR rows per block;
// the previous row's normalized h is carried in registers, so each x row is
// loaded once (vs twice) and reduced once (vs twice). Bit-identical math.
// Requires LNR | T.
// ---------------------------------------------------------------------------
__global__ __launch_bounds__(256) void ln_mix3_b(
    const float* __restrict__ x, const float* __restrict__ g,
    const float* __restrict__ be,
    const float* __restrict__ mx0, const float* __restrict__ mx1,
    const float* __restrict__ mx2,
    ushort* __restrict__ o0, ushort* __restrict__ o1, ushort* __restrict__ o2,
    int T, int C) {
    const long r0 = (long)blockIdx.x * LNR;
    const int tid = threadIdx.x;
    const int i0 = tid * 4;
    const int wv = tid >> 6;
    __shared__ float part[2][4][2];

    const floatx4 gv  = *(const floatx4*)&g[i0];
    const floatx4 bv  = *(const floatx4*)&be[i0];
    const floatx4 mk0 = *(const floatx4*)&mx0[i0];
    const floatx4 mk1 = *(const floatx4*)&mx1[i0];
    const floatx4 mk2 = *(const floatx4*)&mx2[i0];
    const float invC = 1.f / (float)C;

    floatx4 hp = (floatx4)0.f;
    if ((int)(r0 % T) != 0) {
        floatx4 xp = *(const floatx4*)&x[(r0 - 1) * C + i0];
        float s = xp.x + xp.y + xp.z + xp.w;
        float q = xp.x * xp.x + xp.y * xp.y + xp.z * xp.z + xp.w * xp.w;
#pragma unroll
        for (int off = 32; off; off >>= 1) {
            s += __shfl_xor(s, off); q += __shfl_xor(q, off);
        }
        if ((tid & 63) == 0) { part[0][wv][0] = s; part[0][wv][1] = q; }
        __syncthreads();
        s = part[0][0][0] + part[0][1][0] + part[0][2][0] + part[0][3][0];
        q = part[0][0][1] + part[0][1][1] + part[0][2][1] + part[0][3][1];
        float mu = s * invC;
        float rs = rsqrtf(q * invC - mu * mu + LN_EPS);
        hp = (xp - mu) * rs * gv + bv;
        __syncthreads();
    }

    for (int r = 0; r < LNR; ++r) {
        const long row = r0 + r;
        floatx4 xc = *(const floatx4*)&x[row * C + i0];
        float s = xc.x + xc.y + xc.z + xc.w;
        float q = xc.x * xc.x + xc.y * xc.y + xc.z * xc.z + xc.w * xc.w;
#pragma unroll
        for (int off = 32; off; off >>= 1) {
            s += __shfl_xor(s, off); q += __shfl_xor(q, off);
        }
        const int pb = r & 1;
        if ((tid & 63) == 0) { part[pb][wv][0] = s; part[pb][wv][1] = q; }
        __syncthreads();
        s = part[pb][0][0] + part[pb][1][0] + part[pb][2][0] + part[pb][3][0];
        q = part[pb][0][1] + part[pb][1][1] + part[pb][2][1] + part[pb][3][1];
        float mu = s * invC;
        float rs = rsqrtf(q * invC - mu * mu + LN_EPS);
        floatx4 hc = (xc - mu) * rs * gv + bv;

        {
            floatx4 v = hc * mk0 + hp * (1.f - mk0);
            ushort4 pk;
            pk.x = f2bf(v.x); pk.y = f2bf(v.y); pk.z = f2bf(v.z); pk.w = f2bf(v.w);
            *(ushort4*)&o0[row * C + i0] = pk;
        }
        {
            floatx4 v = hc * mk1 + hp * (1.f - mk1);
            ushort4 pk;
            pk.x = f2bf(v.x); pk.y = f2bf(v.y); pk.z = f2bf(v.z); pk.w = f2bf(v.w);
            *(ushort4*)&o1[row * C + i0] = pk;
        }
        {
            floatx4 v = hc * mk2 + hp * (1.f - mk2);
            ushort4 pk;
            pk.x = f2bf(v.x); pk.y = f2bf(v.y); pk.z = f2bf(v.z); pk.w = f2bf(v.w);
            *(ushort4*)&o2[row * C + i0] = pk;
        }
        hp = hc;
    }
}

// ---------------------------------------------------------------------------
// Row-batched: out = x + ry (residual), then LN + shift + 2 mixes.
// Same carry scheme as ln_mix3_b. Requires LNR | T.
// ---------------------------------------------------------------------------
__global__ __launch_bounds__(256) void ln_mix_add_b(
    const float* __restrict__ x, const ushort* __restrict__ ry,
    const float* __restrict__ g, const float* __restrict__ be,
    const float* __restrict__ mx0, const float* __restrict__ mx1,
    float* __restrict__ outx,
    ushort* __restrict__ o0, ushort* __restrict__ o1, int T, int C) {
    const long r0 = (long)blockIdx.x * LNR;
    const int tid = threadIdx.x;
    const int i0 = tid * 4;
    const int wv = tid >> 6;
    __shared__ float part[2][4][2];

    const floatx4 gv  = *(const floatx4*)&g[i0];
    const floatx4 bv  = *(const floatx4*)&be[i0];
    const floatx4 mk0 = *(const floatx4*)&mx0[i0];
    const floatx4 mk1 = *(const floatx4*)&mx1[i0];
    const float invC = 1.f / (float)C;

    floatx4 hp = (floatx4)0.f;
    if ((int)(r0 % T) != 0) {
        floatx4 xp = *(const floatx4*)&x[(r0 - 1) * C + i0];
        ushort4 rp = *(const ushort4*)&ry[(r0 - 1) * C + i0];
        xp.x += bf2f(rp.x); xp.y += bf2f(rp.y); xp.z += bf2f(rp.z); xp.w += bf2f(rp.w);
        float s = xp.x + xp.y + xp.z + xp.w;
        float q = xp.x * xp.x + xp.y * xp.y + xp.z * xp.z + xp.w * xp.w;
#pragma unroll
        for (int off = 32; off; off >>= 1) {
            s += __shfl_xor(s, off); q += __shfl_xor(q, off);
        }
        if ((tid & 63) == 0) { part[0][wv][0] = s; part[0][wv][1] = q; }
        __syncthreads();
        s = part[0][0][0] + part[0][1][0] + part[0][2][0] + part[0][3][0];
        q = part[0][0][1] + part[0][1][1] + part[0][2][1] + part[0][3][1];
        float mu = s * invC;
        float rs = rsqrtf(q * invC - mu * mu + LN_EPS);
        hp = (xp - mu) * rs * gv + bv;
        __syncthreads();
    }

    for (int r = 0; r < LNR; ++r) {
        const long row = r0 + r;
        floatx4 xc = *(const floatx4*)&x[row * C + i0];
        ushort4 rc = *(const ushort4*)&ry[row * C + i0];
        xc.x += bf2f(rc.x); xc.y += bf2f(rc.y); xc.z += bf2f(rc.z); xc.w += bf2f(rc.w);
        *(floatx4*)&outx[row * C + i0] = xc;

        float s = xc.x + xc.y + xc.z + xc.w;
        float q = xc.x * xc.x + xc.y * xc.y + xc.z * xc.z + xc.w * xc.w;
#pragma unroll
        for (int off = 32; off; off >>= 1) {
            s += __shfl_xor(s, off); q += __shfl_xor(q, off);
        }
        const int pb = r & 1;
        if ((tid & 63) == 0) { part[pb][wv][0] = s; part[pb][wv][1] = q; }
        __syncthreads();
        s = part[pb][0][0] + part[pb][1][0] + part[pb][2][0] + part[pb][3][0];
        q = part[pb][0][1] + part[pb][1][1] + part[pb][2][1] + part[pb][3][1];
        float mu = s * invC;
        float rs = rsqrtf(q * invC - mu * mu + LN_EPS);
        floatx4 hc = (xc - mu) * rs * gv + bv;

        {
            floatx4 v = hc * mk0 + hp * (1.f - mk0);
            ushort4 pk;
            pk.x = f2bf(v.x); pk.y = f2bf(v.y); pk.z = f2bf(v.z); pk.w = f2bf(v.w);
            *(ushort4*)&o0[row * C + i0] = pk;
        }
        {
            floatx4 v = hc * mk1 + hp * (1.f - mk1);
            ushort4 pk;
            pk.x = f2bf(v.x); pk.y = f2bf(v.y); pk.z = f2bf(v.z); pk.w = f2bf(v.w);
            *(ushort4*)&o1[row * C + i0] = pk;
        }
        hp = hc;
    }
}

// ===========================================================================
// Segmented exact WKV scan (verified — unchanged).
// ===========================================================================

// K1: per-segment pp from zero state (reads k only)
__global__ __launch_bounds__(256) void wkv_pp_local(
    const float* __restrict__ w, const ushort* __restrict__ k,
    float* __restrict__ pp_loc, int C, int L) {
    const int g = blockIdx.x * 256 + threadIdx.x;
    const int c = g % C;
    const long seg = g / C;
    const float L2E = 1.4426950408889634f;
    const float w2 = w[c] * L2E;
    const ushort* kp = k + seg * L * C + c;
    float pp = -1e38f;
    for (int j = 0; j < L; ++j) {
        float kk = bf2f(kp[(long)j * C]) * L2E;
        float ppw = pp + w2;
        float wk = w2 + kk;
        float p2 = fmaxf(ppw, wk);
        pp = p2 + log2f(exp2f(ppw - p2) + exp2f(wk - p2));
    }
    pp_loc[g] = pp;
}

// K2: sequential pp composition per channel
__global__ __launch_bounds__(256) void wkv_pp_compose(
    const float* __restrict__ w, const float* __restrict__ pp_loc,
    float* __restrict__ pp_in, int C, int SEG, int L) {
    const int g = blockIdx.x * 256 + threadIdx.x;  // b*C + c
    const int c = g % C;
    const long b = g / C;
    const float wL = w[c] * 1.4426950408889634f * (float)L;
    float pp = -1e38f;
    for (int s = 0; s < SEG; ++s) {
        const long idx = (b * SEG + s) * C + c;
        pp_in[idx] = pp;
        float lhs = pp + wL;
        float rhs = pp_loc[idx];
        float m = fmaxf(lhs, rhs);
        pp = m + log2f(exp2f(lhs - m) + exp2f(rhs - m));
    }
}

// K3: per-segment (alpha,beta) on the TRUE pp path
__global__ __launch_bounds__(256) void wkv_ab_local(
    const float* __restrict__ w, const ushort* __restrict__ k,
    const ushort* __restrict__ v, const float* __restrict__ pp_in,
    float* __restrict__ alpha, float* __restrict__ beta, int C, int L) {
    const int g = blockIdx.x * 256 + threadIdx.x;
    const int c = g % C;
    const long seg = g / C;
    const float L2E = 1.4426950408889634f;
    const float w2 = w[c] * L2E;
    const ushort* kp = k + seg * L * C + c;
    const ushort* vp = v + seg * L * C + c;
    float pp = pp_in[g];
    float al = 1.f, be = 0.f;
    for (int j = 0; j < L; ++j) {
        float kk = bf2f(kp[(long)j * C]) * L2E;
        float vv = bf2f(vp[(long)j * C]);
        float ppw = pp + w2;
        float wk = w2 + kk;
        float p2 = fmaxf(ppw, wk);
        float e1u = exp2f(ppw - p2);
        float e2u = exp2f(wk - p2);
        al *= e1u;
        be = e1u * be + e2u * vv;
        pp = p2 + log2f(e1u + e2u);
    }
    alpha[g] = al;
    beta[g] = be;
}

// K4: sequential aa composition per channel
__global__ __launch_bounds__(256) void wkv_aa_compose(
    const float* __restrict__ alpha, const float* __restrict__ beta,
    float* __restrict__ aa_in, int C, int SEG) {
    const int g = blockIdx.x * 256 + threadIdx.x;  // b*C + c
    const int c = g % C;
    const long b = g / C;
    float aa = 0.f;
    for (int s = 0; s < SEG; ++s) {
        const long idx = (b * SEG + s) * C + c;
        aa_in[idx] = aa;
        aa = alpha[idx] * aa + beta[idx];
    }
    (void)c;
}

// K5: per-segment emit with true incoming state: ry = r * y, [M][C] layout
__global__ __launch_bounds__(256) void wkv_emit(
    const float* __restrict__ w, const float* __restrict__ u,
    const ushort* __restrict__ k, const ushort* __restrict__ v,
    const ushort* __restrict__ r, const float* __restrict__ aa_in,
    const float* __restrict__ pp_in, ushort* __restrict__ ry, int C, int L) {
    const int g = blockIdx.x * 256 + threadIdx.x;
    const int c = g % C;
    const long seg = g / C;
    const float L2E = 1.4426950408889634f;
    const float w2 = w[c] * L2E;
    const float u2 = u[c] * L2E;
    const long base = seg * L * C + c;
    const ushort* kp = k + base;
    const ushort* vp = v + base;
    const ushort* rp = r + base;
    ushort* op = ry + base;
    float aa = aa_in[g];
    float pp = pp_in[g];
    for (int j = 0; j < L; ++j) {
        const long o = (long)j * C;
        float kk = bf2f(kp[o]) * L2E;
        float vv = bf2f(vp[o]);
        float uk = u2 + kk;
        float p = fmaxf(pp, uk);
        float e1 = exp2f(pp - p);
        float e2 = exp2f(uk - p);
        float y = __fdividef(e1 * aa + e2 * vv, e1 + e2);
        op[o] = f2bf(bf2f(rp[o]) * y);
        float ppw = pp + w2;
        float wk = w2 + kk;
        float p2 = fmaxf(ppw, wk);
        float e1u = exp2f(ppw - p2);
        float e2u = exp2f(wk - p2);
        aa = e1u * aa + e2u * vv;
        pp = p2 + log2f(e1u + e2u);
    }
}

// out[n][k] = bf16(in[k][n]); in is [K][N] fp32 row-major. block (32,8).
__global__ __launch_bounds__(256) void transpose_bf16(
    const float* __restrict__ in, ushort* __restrict__ out, int K, int N) {
    __shared__ float tile[32][33];
    const int tx = threadIdx.x, ty = threadIdx.y;
    const long k0 = (long)blockIdx.y * 32, n0 = (long)blockIdx.x * 32;
#pragma unroll
    for (int i = 0; i < 4; i++)
        tile[ty + i * 8][tx] = in[(k0 + ty + i * 8) * N + n0 + tx];
    __syncthreads();
#pragma unroll
    for (int i = 0; i < 4; i++)
        out[(n0 + ty + i * 8) * K + k0 + tx] = f2bf(tile[tx][ty + i * 8]);
}

// 4 same-shape (C x C) transposes in one dispatch (blockIdx.z selects pair).
__global__ __launch_bounds__(256) void transpose4_bf16(
    const float* __restrict__ a0, const float* __restrict__ a1,
    const float* __restrict__ a2, const float* __restrict__ a3,
    ushort* __restrict__ b0, ushort* __restrict__ b1,
    ushort* __restrict__ b2, ushort* __restrict__ b3, int K, int N) {
    __shared__ float tile[32][33];
    const int z = blockIdx.z;
    const float* in = (z == 0) ? a0 : (z == 1) ? a1 : (z == 2) ? a2 : a3;
    ushort* out = (z == 0) ? b0 : (z == 1) ? b1 : (z == 2) ? b2 : b3;
    const int tx = threadIdx.x, ty = threadIdx.y;
    const long k0 = (long)blockIdx.y * 32, n0 = (long)blockIdx.x * 32;
#pragma unroll
    for (int i = 0; i < 4; i++)
        tile[ty + i * 8][tx] = in[(k0 + ty + i * 8) * N + n0 + tx];
    __syncthreads();
#pragma unroll
    for (int i = 0; i < 4; i++)
        out[(n0 + ty + i * 8) * K + k0 + tx] = f2bf(tile[tx][ty + i * 8]);
}

extern "C" void kernel_launch(void* const* d_in, const int* in_sizes, int n_in,
                              void* d_out, int out_size, void* d_ws, size_t ws_size,
                              hipStream_t stream) {
    const float* x      = (const float*)d_in[0];
    const float* tdecay = (const float*)d_in[1];
    const float* tfirst = (const float*)d_in[2];
    const float* w_tk   = (const float*)d_in[3];
    const float* w_tv   = (const float*)d_in[4];
    const float* w_tr   = (const float*)d_in[5];
    const float* w_ck   = (const float*)d_in[6];
    const float* w_cv   = (const float*)d_in[7];
    const float* w_cr   = (const float*)d_in[8];
    const float* ln1g   = (const float*)d_in[9];
    const float* ln1b   = (const float*)d_in[10];
    const float* ln2g   = (const float*)d_in[11];
    const float* ln2b   = (const float*)d_in[12];
    const float* mixk   = (const float*)d_in[13];
    const float* mixv   = (const float*)d_in[14];
    const float* mixr   = (const float*)d_in[15];
    const float* cmixk  = (const float*)d_in[16];
    const float* cmixr  = (const float*)d_in[17];
    float* out = (float*)d_out;

    const int C  = in_sizes[1];              // 1024
    const long M = (long)in_sizes[0] / C;    // 16384
    const int T  = 2048;
    const int B  = (int)(M / T);
    const int H  = 2 * C;                    // 2048 = half of 4C
    const int SEG = 64;                      // segments per sequence
    const int L  = T / SEG;                  // 32 steps per segment
    const int NSEG = B * SEG;                // 512 total segments

    // one-time: allow 128 KiB dynamic LDS for gemm256
    static bool s_attr = []() {
        (void)hipFuncSetAttribute((const void*)gemm256<0>,
                                  hipFuncAttributeMaxDynamicSharedMemorySize, 131072);
        (void)hipFuncSetAttribute((const void*)gemm256<1>,
                                  hipFuncAttributeMaxDynamicSharedMemorySize, 131072);
        (void)hipFuncSetAttribute((const void*)gemm256<2>,
                                  hipFuncAttributeMaxDynamicSharedMemorySize, 131072);
        (void)hipFuncSetAttribute((const void*)gemm256<3>,
                                  hipFuncAttributeMaxDynamicSharedMemorySize, 131072);
        return true;
    }();
    (void)s_attr;
    const int SMEM = 131072;

    // workspace layout identical to previous (verified) version
    const size_t MBy = 1024ull * 1024ull;
    char* w8 = (char*)d_ws;
    ushort* wT_tk  = (ushort*)(w8 + 0 * MBy);
    ushort* wT_tv  = (ushort*)(w8 + 2 * MBy);
    ushort* wT_tr  = (ushort*)(w8 + 4 * MBy);
    ushort* wT_cr  = (ushort*)(w8 + 6 * MBy);
    ushort* wT_ck  = (ushort*)(w8 + 8 * MBy);
    ushort* wT_cv0 = (ushort*)(w8 + 16 * MBy);
    ushort* wT_cv1 = (ushort*)(w8 + 20 * MBy);
    ushort* xk     = (ushort*)(w8 + 24 * MBy);
    ushort* xv     = (ushort*)(w8 + 56 * MBy);
    ushort* xr     = (ushort*)(w8 + 88 * MBy);
    ushort* kbuf   = (ushort*)(w8 + 120 * MBy);
    ushort* vbuf   = (ushort*)(w8 + 152 * MBy);
    ushort* rbuf   = (ushort*)(w8 + 24 * MBy);   // xk dead
    float*  pp_loc = (float*)(w8 + 56 * MBy);    // xv dead (2MB each)
    float*  pp_in  = (float*)(w8 + 58 * MBy);
    float*  alpha  = (float*)(w8 + 60 * MBy);
    float*  beta   = (float*)(w8 + 62 * MBy);
    float*  aa_in  = (float*)(w8 + 64 * MBy);
    ushort* ry     = (ushort*)(w8 + 88 * MBy);   // xr dead
    ushort* ck     = (ushort*)(w8 + 120 * MBy);  // kbuf dead
    ushort* cr     = (ushort*)(w8 + 152 * MBy);  // vbuf dead
    ushort* scr    = (ushort*)(w8 + 24 * MBy);   // rbuf dead
    ushort* kkbuf  = (ushort*)(w8 + 56 * MBy);   // states/ry dead, 64MB

    dim3 tb(32, 8);
    transpose4_bf16<<<dim3(C / 32, C / 32, 4), tb, 0, stream>>>(
        w_tk, w_tv, w_tr, w_cr, wT_tk, wT_tv, wT_tr, wT_cr, C, C);
    transpose_bf16<<<dim3(4 * C / 32, C / 32), tb, 0, stream>>>(w_ck, wT_ck, C, 4 * C);
    transpose_bf16<<<dim3(C / 32, H / 32), tb, 0, stream>>>(w_cv, wT_cv0, H, C);
    transpose_bf16<<<dim3(C / 32, H / 32), tb, 0, stream>>>(w_cv + (long)H * C, wT_cv1, H, C);

    ln_mix3_b<<<(int)(M / LNR), 256, 0, stream>>>(x, ln1g, ln1b, mixk, mixv, mixr,
                                                  xk, xv, xr, T, C);

    dim3 g256(C / 256, (int)(M / 256));
    gemm256<0><<<g256, 512, SMEM, stream>>>(xk, wT_tk, C, C, C, C,
                                            nullptr, kbuf, nullptr, nullptr);
    gemm256<0><<<g256, 512, SMEM, stream>>>(xv, wT_tv, C, C, C, C,
                                            nullptr, vbuf, nullptr, nullptr);
    gemm256<1><<<g256, 512, SMEM, stream>>>(xr, wT_tr, C, C, C, C,
                                            nullptr, rbuf, nullptr, nullptr);

    // segmented exact WKV scan
    const int segthreads = NSEG * C;                     // 524288
    wkv_pp_local<<<segthreads / 256, 256, 0, stream>>>(tdecay, kbuf, pp_loc, C, L);
    wkv_pp_compose<<<(B * C) / 256, 256, 0, stream>>>(tdecay, pp_loc, pp_in, C, SEG, L);
    wkv_ab_local<<<segthreads / 256, 256, 0, stream>>>(tdecay, kbuf, vbuf, pp_in,
                                                       alpha, beta, C, L);
    wkv_aa_compose<<<(B * C) / 256, 256, 0, stream>>>(alpha, beta, aa_in, C, SEG);
    wkv_emit<<<segthreads / 256, 256, 0, stream>>>(tdecay, tfirst, kbuf, vbuf, rbuf,
                                                   aa_in, pp_in, ry, C, L);

    // fused: out = x + ry, then LN2 + shift + channel mixes
    ln_mix_add_b<<<(int)(M / LNR), 256, 0, stream>>>(x, ry, ln2g, ln2b, cmixk, cmixr,
                                                     out, ck, cr, T, C);

    gemm256<1><<<g256, 512, SMEM, stream>>>(cr, wT_cr, C, C, C, C,
                                            nullptr, scr, nullptr, nullptr);

    // channel-mix hidden (4C) processed in two 2C halves through one 64MB buffer
    for (int h = 0; h < 2; ++h) {
        const ushort* wck_h = wT_ck + (long)h * H * C;
        const ushort* wcv_h = (h == 0) ? wT_cv0 : wT_cv1;
        gemm256<2><<<dim3(H / 256, (int)(M / 256)), 512, SMEM, stream>>>(
            ck, wck_h, C, C, C, H, nullptr, kkbuf, nullptr, nullptr);
        gemm256<3><<<g256, 512, SMEM, stream>>>(
            kkbuf, wcv_h, H, H, H, C, out, nullptr, out, scr);
    }
}

// Round 10
// 875.761 us; speedup vs baseline: 1.3179x; 1.0075x over previous
//
#include <hip/hip_runtime.h>
#include <hip/hip_bf16.h>
#include <stdint.h>

#define LN_EPS 1e-5f
#define LNR 8

typedef __attribute__((ext_vector_type(8))) __bf16 bf16x8;
typedef __attribute__((ext_vector_type(8))) short short8;
typedef __attribute__((ext_vector_type(4))) float floatx4;

__device__ __forceinline__ ushort f2bf(float f) {
    __hip_bfloat16 h = __float2bfloat16(f);
    return *reinterpret_cast<ushort*>(&h);
}
__device__ __forceinline__ float bf2f(ushort u) {
    return __builtin_bit_cast(float, ((unsigned int)u) << 16);
}

// async global->LDS, 16B per lane; LDS dest = wave-uniform base + lane*16
__device__ __forceinline__ void gload16(const void* g, void* l) {
#if __has_builtin(__builtin_amdgcn_global_load_lds)
    __builtin_amdgcn_global_load_lds(
        (const __attribute__((address_space(1))) unsigned int*)g,
        (__attribute__((address_space(3))) unsigned int*)l, 16, 0, 0);
#else
    *(int4*)l = *(const int4*)g;
#endif
}

#define SBAR __builtin_amdgcn_s_barrier()
#define SCHED0 __builtin_amdgcn_sched_barrier(0)
#define WAIT_LGKM0 asm volatile("s_waitcnt lgkmcnt(0)" ::: "memory")
#define WAIT_VM4 asm volatile("s_waitcnt vmcnt(4)" ::: "memory")
#define WAIT_VM0 asm volatile("s_waitcnt vmcnt(0)" ::: "memory")

// ---------------------------------------------------------------------------
// GEMM: C[M,N] = A[M,K](bf16 rm, lda) x Bt[N,K](bf16 rm, ldb)  (Bt = B^T)
// 256x256 tile, BK=64, 512 thr (8 waves 2Mx4N, each 128x64 out).
// ROUND-10 CHANGE: 2 MFMA phases per K-tile (was 4) — at these short-K
// shapes the schedule was barrier-dominated (MfmaUtil 24% with MFMA work
// only ~8us of 112us/block). Barriers 8->4, lgkm waits 4->2 per K-tile;
// staging order and counted-vmcnt arithmetic unchanged; vmcnt placed AFTER
// phase-B's MFMA cluster so staging flies under compute.
// EPI: 0 bf16 | 1 bf16 sigmoid | 2 bf16 relu^2 | 3 f32 out=add0+mul0*acc
// ---------------------------------------------------------------------------
#define STAGE_A(h, t)                                                        \
    do {                                                                     \
        ushort* _d = &lds[((((t) & 1) * 2 + 0) * 2 + (h)) * 8192];           \
        const long _o = (long)(h) * 128 * lda + (long)(t) * 64;              \
        gload16(aS0 + _o, _d + tid * 8);                                     \
        gload16(aS1 + _o, _d + (tid + 512) * 8);                             \
    } while (0)
#define STAGE_B(h, t)                                                        \
    do {                                                                     \
        ushort* _d = &lds[((((t) & 1) * 2 + 1) * 2 + (h)) * 8192];           \
        const long _o = (long)(h) * 128 * ldb + (long)(t) * 64;              \
        gload16(bS0 + _o, _d + tid * 8);                                     \
        gload16(bS1 + _o, _d + (tid + 512) * 8);                             \
    } while (0)
#define GEMM_LDA(MB)                                                         \
    _Pragma("unroll") for (int mi = 0; mi < 4; ++mi)                         \
    _Pragma("unroll") for (int ks = 0; ks < 2; ++ks)                         \
        a[mi][ks] = __builtin_bit_cast(                                      \
            bf16x8, *(const short8*)&ldsA[((MB) + mi) * 1024 + ks * 512 + aoff]);
#define GEMM_LDB(NB)                                                         \
    _Pragma("unroll") for (int ni = 0; ni < 2; ++ni)                         \
    _Pragma("unroll") for (int ks = 0; ks < 2; ++ks)                         \
        b[(NB) + ni][ks] = __builtin_bit_cast(                               \
            bf16x8, *(const short8*)&ldsB[((NB) + ni) * 1024 + ks * 512 + boff]);
#define GEMM_MFMA(MB, NB)                                                    \
    __builtin_amdgcn_s_setprio(1);                                           \
    _Pragma("unroll") for (int mi = 0; mi < 4; ++mi)                         \
    _Pragma("unroll") for (int ni = 0; ni < 2; ++ni)                         \
    _Pragma("unroll") for (int ks = 0; ks < 2; ++ks)                         \
        acc[(MB) + mi][(NB) + ni] = __builtin_amdgcn_mfma_f32_16x16x32_bf16( \
            a[mi][ks], b[(NB) + ni][ks], acc[(MB) + mi][(NB) + ni], 0, 0, 0);\
    __builtin_amdgcn_s_setprio(0);

template <int EPI>
__global__ __launch_bounds__(512, 2) void gemm256(
    const ushort* __restrict__ A, const ushort* __restrict__ Bt,
    int K, int lda, int ldb, int ldc,
    float* __restrict__ outF, ushort* __restrict__ outB,
    const float* __restrict__ add0, const ushort* __restrict__ mul0) {
    extern __shared__ ushort lds[];

    const int tid  = threadIdx.x;
    const int lane = tid & 63;
    const int quad = lane >> 4;
    const int l16  = lane & 15;
    const int wv   = tid >> 6;      // 0..7
    const int wmi  = wv >> 2;       // 0..1 -> rows wmi*128 (A half = wmi)
    const int wni  = wv & 3;        // 0..3 -> cols wni*64  (B half = wni>>1)

    // XCD-chunked bijective swizzle, column-major tile order (measured: null
    // vs row-major but kept — it is the measured 882us configuration).
    const int gx  = gridDim.x;
    const int gy  = gridDim.y;
    const int nwg = gx * gy;
    int b_ = blockIdx.y * gx + blockIdx.x;
    b_ = (b_ & 7) * (nwg >> 3) + (b_ >> 3);
    const long m0 = (long)(b_ % gy) * 256;
    const long n0 = (long)(b_ / gy) * 256;

    floatx4 acc[8][4];
#pragma unroll
    for (int i = 0; i < 8; ++i)
#pragma unroll
        for (int j = 0; j < 4; ++j) acc[i][j] = (floatx4)0.f;

    // staging slot decode: slot j (16B) -> rowInHalf, col (fragment order)
    const int j1 = tid + 512;
    const int r0 = ((tid >> 7) << 4) + (tid & 15);
    const int c0 = (tid >> 4) & 7;
    const int col0 = (c0 & 3) * 8 + (c0 >> 2) * 32;
    const int r1 = ((j1 >> 7) << 4) + (j1 & 15);
    const int c1 = (j1 >> 4) & 7;
    const int col1 = (c1 & 3) * 8 + (c1 >> 2) * 32;
    const ushort* aS0 = A + (m0 + r0) * (long)lda + col0;
    const ushort* aS1 = A + (m0 + r1) * (long)lda + col1;
    const ushort* bS0 = Bt + (n0 + r0) * (long)ldb + col0;
    const ushort* bS1 = Bt + (n0 + r1) * (long)ldb + col1;

    const int aoff = quad * 128 + l16 * 8;                      // ushort units
    const int boff = (wni & 1) * 4096 + quad * 128 + l16 * 8;

    const int NT = K >> 6;

    // prologue: tile0 {A0,A1,B0,B1} + tile1 {B0,B1}; keep last 2 halves in flight
    STAGE_A(0, 0); STAGE_A(1, 0);
    STAGE_B(0, 0); STAGE_B(1, 0);
    if (NT > 1) { STAGE_B(0, 1); STAGE_B(1, 1); WAIT_VM4; }
    else        { WAIT_VM0; }
    SBAR;

    bf16x8 a[4][2], b[4][2];
    for (int kt = 0; kt < NT; ++kt) {
        const int d = kt & 1;
        const ushort* ldsA = &lds[((d * 2 + 0) * 2 + wmi) * 8192];
        const ushort* ldsB = &lds[((d * 2 + 1) * 2 + (wni >> 1)) * 8192];

        // Phase A: read a0-3 + b0-3 ; stage A0,A1(kt+1) ; MFMA m0-3 x n0-3
        GEMM_LDA(0)
        GEMM_LDB(0)
        GEMM_LDB(2)
        if (kt + 1 < NT) { STAGE_A(0, kt + 1); STAGE_A(1, kt + 1); }
        SBAR; WAIT_LGKM0; SCHED0;
        GEMM_MFMA(0, 0)
        GEMM_MFMA(0, 2)
        SCHED0; SBAR;

        // Phase B: read a4-7 (reuse a regs) ; stage B0,B1(kt+2) ; MFMA m4-7
        // x n0-3 ; counted vmcnt AFTER the cluster (staging hides under MFMA)
        GEMM_LDA(4)
        if (kt + 2 < NT) { STAGE_B(0, kt + 2); STAGE_B(1, kt + 2); }
        SBAR; WAIT_LGKM0; SCHED0;
        GEMM_MFMA(4, 0)
        GEMM_MFMA(4, 2)
        SCHED0;
        if (kt < NT - 2) { WAIT_VM4; } else { WAIT_VM0; }
        SBAR;
    }

    // C/D layout: col = lane&15, row = quad*4 + reg (m89/m91-verified)
#pragma unroll
    for (int mi = 0; mi < 8; ++mi) {
#pragma unroll
        for (int ni = 0; ni < 4; ++ni) {
            const long n = n0 + wni * 64 + ni * 16 + l16;
#pragma unroll
            for (int r = 0; r < 4; ++r) {
                const long m = m0 + wmi * 128 + mi * 16 + quad * 4 + r;
                const long idx = m * (long)ldc + n;
                float v = acc[mi][ni][r];
                if constexpr (EPI == 0) {
                    outB[idx] = f2bf(v);
                } else if constexpr (EPI == 1) {
                    outB[idx] = f2bf(1.f / (1.f + __expf(-v)));
                } else if constexpr (EPI == 2) {
                    float t = fmaxf(v, 0.f);
                    outB[idx] = f2bf(t * t);
                } else if constexpr (EPI == 3) {
                    outF[idx] = add0[idx] + bf2f(mul0[idx]) * v;
                }
            }
        }
    }
}

// ---------------------------------------------------------------------------
// Row-batched LayerNorm + time-shift + mix (3 outputs). LNR rows per block;
// previous row's normalized h carried in registers. Verified (round 9).
// ---------------------------------------------------------------------------
__global__ __launch_bounds__(256) void ln_mix3_b(
    const float* __restrict__ x, const float* __restrict__ g,
    const float* __restrict__ be,
    const float* __restrict__ mx0, const float* __restrict__ mx1,
    const float* __restrict__ mx2,
    ushort* __restrict__ o0, ushort* __restrict__ o1, ushort* __restrict__ o2,
    int T, int C) {
    const long r0 = (long)blockIdx.x * LNR;
    const int tid = threadIdx.x;
    const int i0 = tid * 4;
    const int wv = tid >> 6;
    __shared__ float part[2][4][2];

    const floatx4 gv  = *(const floatx4*)&g[i0];
    const floatx4 bv  = *(const floatx4*)&be[i0];
    const floatx4 mk0 = *(const floatx4*)&mx0[i0];
    const floatx4 mk1 = *(const floatx4*)&mx1[i0];
    const floatx4 mk2 = *(const floatx4*)&mx2[i0];
    const float invC = 1.f / (float)C;

    floatx4 hp = (floatx4)0.f;
    if ((int)(r0 % T) != 0) {
        floatx4 xp = *(const floatx4*)&x[(r0 - 1) * C + i0];
        float s = xp.x + xp.y + xp.z + xp.w;
        float q = xp.x * xp.x + xp.y * xp.y + xp.z * xp.z + xp.w * xp.w;
#pragma unroll
        for (int off = 32; off; off >>= 1) {
            s += __shfl_xor(s, off); q += __shfl_xor(q, off);
        }
        if ((tid & 63) == 0) { part[0][wv][0] = s; part[0][wv][1] = q; }
        __syncthreads();
        s = part[0][0][0] + part[0][1][0] + part[0][2][0] + part[0][3][0];
        q = part[0][0][1] + part[0][1][1] + part[0][2][1] + part[0][3][1];
        float mu = s * invC;
        float rs = rsqrtf(q * invC - mu * mu + LN_EPS);
        hp = (xp - mu) * rs * gv + bv;
        __syncthreads();
    }

    for (int r = 0; r < LNR; ++r) {
        const long row = r0 + r;
        floatx4 xc = *(const floatx4*)&x[row * C + i0];
        float s = xc.x + xc.y + xc.z + xc.w;
        float q = xc.x * xc.x + xc.y * xc.y + xc.z * xc.z + xc.w * xc.w;
#pragma unroll
        for (int off = 32; off; off >>= 1) {
            s += __shfl_xor(s, off); q += __shfl_xor(q, off);
        }
        const int pb = r & 1;
        if ((tid & 63) == 0) { part[pb][wv][0] = s; part[pb][wv][1] = q; }
        __syncthreads();
        s = part[pb][0][0] + part[pb][1][0] + part[pb][2][0] + part[pb][3][0];
        q = part[pb][0][1] + part[pb][1][1] + part[pb][2][1] + part[pb][3][1];
        float mu = s * invC;
        float rs = rsqrtf(q * invC - mu * mu + LN_EPS);
        floatx4 hc = (xc - mu) * rs * gv + bv;

        {
            floatx4 v = hc * mk0 + hp * (1.f - mk0);
            ushort4 pk;
            pk.x = f2bf(v.x); pk.y = f2bf(v.y); pk.z = f2bf(v.z); pk.w = f2bf(v.w);
            *(ushort4*)&o0[row * C + i0] = pk;
        }
        {
            floatx4 v = hc * mk1 + hp * (1.f - mk1);
            ushort4 pk;
            pk.x = f2bf(v.x); pk.y = f2bf(v.y); pk.z = f2bf(v.z); pk.w = f2bf(v.w);
            *(ushort4*)&o1[row * C + i0] = pk;
        }
        {
            floatx4 v = hc * mk2 + hp * (1.f - mk2);
            ushort4 pk;
            pk.x = f2bf(v.x); pk.y = f2bf(v.y); pk.z = f2bf(v.z); pk.w = f2bf(v.w);
            *(ushort4*)&o2[row * C + i0] = pk;
        }
        hp = hc;
    }
}

// ---------------------------------------------------------------------------
// Row-batched: out = x + ry (residual), then LN + shift + 2 mixes.
// Verified (round 9).
// ---------------------------------------------------------------------------
__global__ __launch_bounds__(256) void ln_mix_add_b(
    const float* __restrict__ x, const ushort* __restrict__ ry,
    const float* __restrict__ g, const float* __restrict__ be,
    const float* __restrict__ mx0, const float* __restrict__ mx1,
    float* __restrict__ outx,
    ushort* __restrict__ o0, ushort* __restrict__ o1, int T, int C) {
    const long r0 = (long)blockIdx.x * LNR;
    const int tid = threadIdx.x;
    const int i0 = tid * 4;
    const int wv = tid >> 6;
    __shared__ float part[2][4][2];

    const floatx4 gv  = *(const floatx4*)&g[i0];
    const floatx4 bv  = *(const floatx4*)&be[i0];
    const floatx4 mk0 = *(const floatx4*)&mx0[i0];
    const floatx4 mk1 = *(const floatx4*)&mx1[i0];
    const float invC = 1.f / (float)C;

    floatx4 hp = (floatx4)0.f;
    if ((int)(r0 % T) != 0) {
        floatx4 xp = *(const floatx4*)&x[(r0 - 1) * C + i0];
        ushort4 rp = *(const ushort4*)&ry[(r0 - 1) * C + i0];
        xp.x += bf2f(rp.x); xp.y += bf2f(rp.y); xp.z += bf2f(rp.z); xp.w += bf2f(rp.w);
        float s = xp.x + xp.y + xp.z + xp.w;
        float q = xp.x * xp.x + xp.y * xp.y + xp.z * xp.z + xp.w * xp.w;
#pragma unroll
        for (int off = 32; off; off >>= 1) {
            s += __shfl_xor(s, off); q += __shfl_xor(q, off);
        }
        if ((tid & 63) == 0) { part[0][wv][0] = s; part[0][wv][1] = q; }
        __syncthreads();
        s = part[0][0][0] + part[0][1][0] + part[0][2][0] + part[0][3][0];
        q = part[0][0][1] + part[0][1][1] + part[0][2][1] + part[0][3][1];
        float mu = s * invC;
        float rs = rsqrtf(q * invC - mu * mu + LN_EPS);
        hp = (xp - mu) * rs * gv + bv;
        __syncthreads();
    }

    for (int r = 0; r < LNR; ++r) {
        const long row = r0 + r;
        floatx4 xc = *(const floatx4*)&x[row * C + i0];
        ushort4 rc = *(const ushort4*)&ry[row * C + i0];
        xc.x += bf2f(rc.x); xc.y += bf2f(rc.y); xc.z += bf2f(rc.z); xc.w += bf2f(rc.w);
        *(floatx4*)&outx[row * C + i0] = xc;

        float s = xc.x + xc.y + xc.z + xc.w;
        float q = xc.x * xc.x + xc.y * xc.y + xc.z * xc.z + xc.w * xc.w;
#pragma unroll
        for (int off = 32; off; off >>= 1) {
            s += __shfl_xor(s, off); q += __shfl_xor(q, off);
        }
        const int pb = r & 1;
        if ((tid & 63) == 0) { part[pb][wv][0] = s; part[pb][wv][1] = q; }
        __syncthreads();
        s = part[pb][0][0] + part[pb][1][0] + part[pb][2][0] + part[pb][3][0];
        q = part[pb][0][1] + part[pb][1][1] + part[pb][2][1] + part[pb][3][1];
        float mu = s * invC;
        float rs = rsqrtf(q * invC - mu * mu + LN_EPS);
        floatx4 hc = (xc - mu) * rs * gv + bv;

        {
            floatx4 v = hc * mk0 + hp * (1.f - mk0);
            ushort4 pk;
            pk.x = f2bf(v.x); pk.y = f2bf(v.y); pk.z = f2bf(v.z); pk.w = f2bf(v.w);
            *(ushort4*)&o0[row * C + i0] = pk;
        }
        {
            floatx4 v = hc * mk1 + hp * (1.f - mk1);
            ushort4 pk;
            pk.x = f2bf(v.x); pk.y = f2bf(v.y); pk.z = f2bf(v.z); pk.w = f2bf(v.w);
            *(ushort4*)&o1[row * C + i0] = pk;
        }
        hp = hc;
    }
}

// ===========================================================================
// Segmented exact WKV scan (verified — unchanged).
// ===========================================================================

// K1: per-segment pp from zero state (reads k only)
__global__ __launch_bounds__(256) void wkv_pp_local(
    const float* __restrict__ w, const ushort* __restrict__ k,
    float* __restrict__ pp_loc, int C, int L) {
    const int g = blockIdx.x * 256 + threadIdx.x;
    const int c = g % C;
    const long seg = g / C;
    const float L2E = 1.4426950408889634f;
    const float w2 = w[c] * L2E;
    const ushort* kp = k + seg * L * C + c;
    float pp = -1e38f;
    for (int j = 0; j < L; ++j) {
        float kk = bf2f(kp[(long)j * C]) * L2E;
        float ppw = pp + w2;
        float wk = w2 + kk;
        float p2 = fmaxf(ppw, wk);
        pp = p2 + log2f(exp2f(ppw - p2) + exp2f(wk - p2));
    }
    pp_loc[g] = pp;
}

// K2: sequential pp composition per channel
__global__ __launch_bounds__(256) void wkv_pp_compose(
    const float* __restrict__ w, const float* __restrict__ pp_loc,
    float* __restrict__ pp_in, int C, int SEG, int L) {
    const int g = blockIdx.x * 256 + threadIdx.x;  // b*C + c
    const int c = g % C;
    const long b = g / C;
    const float wL = w[c] * 1.4426950408889634f * (float)L;
    float pp = -1e38f;
    for (int s = 0; s < SEG; ++s) {
        const long idx = (b * SEG + s) * C + c;
        pp_in[idx] = pp;
        float lhs = pp + wL;
        float rhs = pp_loc[idx];
        float m = fmaxf(lhs, rhs);
        pp = m + log2f(exp2f(lhs - m) + exp2f(rhs - m));
    }
}

// K3: per-segment (alpha,beta) on the TRUE pp path
__global__ __launch_bounds__(256) void wkv_ab_local(
    const float* __restrict__ w, const ushort* __restrict__ k,
    const ushort* __restrict__ v, const float* __restrict__ pp_in,
    float* __restrict__ alpha, float* __restrict__ beta, int C, int L) {
    const int g = blockIdx.x * 256 + threadIdx.x;
    const int c = g % C;
    const long seg = g / C;
    const float L2E = 1.4426950408889634f;
    const float w2 = w[c] * L2E;
    const ushort* kp = k + seg * L * C + c;
    const ushort* vp = v + seg * L * C + c;
    float pp = pp_in[g];
    float al = 1.f, be = 0.f;
    for (int j = 0; j < L; ++j) {
        float kk = bf2f(kp[(long)j * C]) * L2E;
        float vv = bf2f(vp[(long)j * C]);
        float ppw = pp + w2;
        float wk = w2 + kk;
        float p2 = fmaxf(ppw, wk);
        float e1u = exp2f(ppw - p2);
        float e2u = exp2f(wk - p2);
        al *= e1u;
        be = e1u * be + e2u * vv;
        pp = p2 + log2f(e1u + e2u);
    }
    alpha[g] = al;
    beta[g] = be;
}

// K4: sequential aa composition per channel
__global__ __launch_bounds__(256) void wkv_aa_compose(
    const float* __restrict__ alpha, const float* __restrict__ beta,
    float* __restrict__ aa_in, int C, int SEG) {
    const int g = blockIdx.x * 256 + threadIdx.x;  // b*C + c
    const int c = g % C;
    const long b = g / C;
    float aa = 0.f;
    for (int s = 0; s < SEG; ++s) {
        const long idx = (b * SEG + s) * C + c;
        aa_in[idx] = aa;
        aa = alpha[idx] * aa + beta[idx];
    }
    (void)c;
}

// K5: per-segment emit with true incoming state: ry = r * y, [M][C] layout
__global__ __launch_bounds__(256) void wkv_emit(
    const float* __restrict__ w, const float* __restrict__ u,
    const ushort* __restrict__ k, const ushort* __restrict__ v,
    const ushort* __restrict__ r, const float* __restrict__ aa_in,
    const float* __restrict__ pp_in, ushort* __restrict__ ry, int C, int L) {
    const int g = blockIdx.x * 256 + threadIdx.x;
    const int c = g % C;
    const long seg = g / C;
    const float L2E = 1.4426950408889634f;
    const float w2 = w[c] * L2E;
    const float u2 = u[c] * L2E;
    const long base = seg * L * C + c;
    const ushort* kp = k + base;
    const ushort* vp = v + base;
    const ushort* rp = r + base;
    ushort* op = ry + base;
    float aa = aa_in[g];
    float pp = pp_in[g];
    for (int j = 0; j < L; ++j) {
        const long o = (long)j * C;
        float kk = bf2f(kp[o]) * L2E;
        float vv = bf2f(vp[o]);
        float uk = u2 + kk;
        float p = fmaxf(pp, uk);
        float e1 = exp2f(pp - p);
        float e2 = exp2f(uk - p);
        float y = __fdividef(e1 * aa + e2 * vv, e1 + e2);
        op[o] = f2bf(bf2f(rp[o]) * y);
        float ppw = pp + w2;
        float wk = w2 + kk;
        float p2 = fmaxf(ppw, wk);
        float e1u = exp2f(ppw - p2);
        float e2u = exp2f(wk - p2);
        aa = e1u * aa + e2u * vv;
        pp = p2 + log2f(e1u + e2u);
    }
}

// out[n][k] = bf16(in[k][n]); in is [K][N] fp32 row-major. block (32,8).
__global__ __launch_bounds__(256) void transpose_bf16(
    const float* __restrict__ in, ushort* __restrict__ out, int K, int N) {
    __shared__ float tile[32][33];
    const int tx = threadIdx.x, ty = threadIdx.y;
    const long k0 = (long)blockIdx.y * 32, n0 = (long)blockIdx.x * 32;
#pragma unroll
    for (int i = 0; i < 4; i++)
        tile[ty + i * 8][tx] = in[(k0 + ty + i * 8) * N + n0 + tx];
    __syncthreads();
#pragma unroll
    for (int i = 0; i < 4; i++)
        out[(n0 + ty + i * 8) * K + k0 + tx] = f2bf(tile[tx][ty + i * 8]);
}

// 4 same-shape (C x C) transposes in one dispatch (blockIdx.z selects pair).
__global__ __launch_bounds__(256) void transpose4_bf16(
    const float* __restrict__ a0, const float* __restrict__ a1,
    const float* __restrict__ a2, const float* __restrict__ a3,
    ushort* __restrict__ b0, ushort* __restrict__ b1,
    ushort* __restrict__ b2, ushort* __restrict__ b3, int K, int N) {
    __shared__ float tile[32][33];
    const int z = blockIdx.z;
    const float* in = (z == 0) ? a0 : (z == 1) ? a1 : (z == 2) ? a2 : a3;
    ushort* out = (z == 0) ? b0 : (z == 1) ? b1 : (z == 2) ? b2 : b3;
    const int tx = threadIdx.x, ty = threadIdx.y;
    const long k0 = (long)blockIdx.y * 32, n0 = (long)blockIdx.x * 32;
#pragma unroll
    for (int i = 0; i < 4; i++)
        tile[ty + i * 8][tx] = in[(k0 + ty + i * 8) * N + n0 + tx];
    __syncthreads();
#pragma unroll
    for (int i = 0; i < 4; i++)
        out[(n0 + ty + i * 8) * K + k0 + tx] = f2bf(tile[tx][ty + i * 8]);
}

extern "C" void kernel_launch(void* const* d_in, const int* in_sizes, int n_in,
                              void* d_out, int out_size, void* d_ws, size_t ws_size,
                              hipStream_t stream) {
    const float* x      = (const float*)d_in[0];
    const float* tdecay = (const float*)d_in[1];
    const float* tfirst = (const float*)d_in[2];
    const float* w_tk   = (const float*)d_in[3];
    const float* w_tv   = (const float*)d_in[4];
    const float* w_tr   = (const float*)d_in[5];
    const float* w_ck   = (const float*)d_in[6];
    const float* w_cv   = (const float*)d_in[7];
    const float* w_cr   = (const float*)d_in[8];
    const float* ln1g   = (const float*)d_in[9];
    const float* ln1b   = (const float*)d_in[10];
    const float* ln2g   = (const float*)d_in[11];
    const float* ln2b   = (const float*)d_in[12];
    const float* mixk   = (const float*)d_in[13];
    const float* mixv   = (const float*)d_in[14];
    const float* mixr   = (const float*)d_in[15];
    const float* cmixk  = (const float*)d_in[16];
    const float* cmixr  = (const float*)d_in[17];
    float* out = (float*)d_out;

    const int C  = in_sizes[1];              // 1024
    const long M = (long)in_sizes[0] / C;    // 16384
    const int T  = 2048;
    const int B  = (int)(M / T);
    const int H  = 2 * C;                    // 2048 = half of 4C
    const int SEG = 64;                      // segments per sequence
    const int L  = T / SEG;                  // 32 steps per segment
    const int NSEG = B * SEG;                // 512 total segments

    // one-time: allow 128 KiB dynamic LDS for gemm256
    static bool s_attr = []() {
        (void)hipFuncSetAttribute((const void*)gemm256<0>,
                                  hipFuncAttributeMaxDynamicSharedMemorySize, 131072);
        (void)hipFuncSetAttribute((const void*)gemm256<1>,
                                  hipFuncAttributeMaxDynamicSharedMemorySize, 131072);
        (void)hipFuncSetAttribute((const void*)gemm256<2>,
                                  hipFuncAttributeMaxDynamicSharedMemorySize, 131072);
        (void)hipFuncSetAttribute((const void*)gemm256<3>,
                                  hipFuncAttributeMaxDynamicSharedMemorySize, 131072);
        return true;
    }();
    (void)s_attr;
    const int SMEM = 131072;

    // workspace layout identical to previous (verified) version
    const size_t MBy = 1024ull * 1024ull;
    char* w8 = (char*)d_ws;
    ushort* wT_tk  = (ushort*)(w8 + 0 * MBy);
    ushort* wT_tv  = (ushort*)(w8 + 2 * MBy);
    ushort* wT_tr  = (ushort*)(w8 + 4 * MBy);
    ushort* wT_cr  = (ushort*)(w8 + 6 * MBy);
    ushort* wT_ck  = (ushort*)(w8 + 8 * MBy);
    ushort* wT_cv0 = (ushort*)(w8 + 16 * MBy);
    ushort* wT_cv1 = (ushort*)(w8 + 20 * MBy);
    ushort* xk     = (ushort*)(w8 + 24 * MBy);
    ushort* xv     = (ushort*)(w8 + 56 * MBy);
    ushort* xr     = (ushort*)(w8 + 88 * MBy);
    ushort* kbuf   = (ushort*)(w8 + 120 * MBy);
    ushort* vbuf   = (ushort*)(w8 + 152 * MBy);
    ushort* rbuf   = (ushort*)(w8 + 24 * MBy);   // xk dead
    float*  pp_loc = (float*)(w8 + 56 * MBy);    // xv dead (2MB each)
    float*  pp_in  = (float*)(w8 + 58 * MBy);
    float*  alpha  = (float*)(w8 + 60 * MBy);
    float*  beta   = (float*)(w8 + 62 * MBy);
    float*  aa_in  = (float*)(w8 + 64 * MBy);
    ushort* ry     = (ushort*)(w8 + 88 * MBy);   // xr dead
    ushort* ck     = (ushort*)(w8 + 120 * MBy);  // kbuf dead
    ushort* cr     = (ushort*)(w8 + 152 * MBy);  // vbuf dead
    ushort* scr    = (ushort*)(w8 + 24 * MBy);   // rbuf dead
    ushort* kkbuf  = (ushort*)(w8 + 56 * MBy);   // states/ry dead, 64MB

    dim3 tb(32, 8);
    transpose4_bf16<<<dim3(C / 32, C / 32, 4), tb, 0, stream>>>(
        w_tk, w_tv, w_tr, w_cr, wT_tk, wT_tv, wT_tr, wT_cr, C, C);
    transpose_bf16<<<dim3(4 * C / 32, C / 32), tb, 0, stream>>>(w_ck, wT_ck, C, 4 * C);
    transpose_bf16<<<dim3(C / 32, H / 32), tb, 0, stream>>>(w_cv, wT_cv0, H, C);
    transpose_bf16<<<dim3(C / 32, H / 32), tb, 0, stream>>>(w_cv + (long)H * C, wT_cv1, H, C);

    ln_mix3_b<<<(int)(M / LNR), 256, 0, stream>>>(x, ln1g, ln1b, mixk, mixv, mixr,
                                                  xk, xv, xr, T, C);

    dim3 g256(C / 256, (int)(M / 256));
    gemm256<0><<<g256, 512, SMEM, stream>>>(xk, wT_tk, C, C, C, C,
                                            nullptr, kbuf, nullptr, nullptr);
    gemm256<0><<<g256, 512, SMEM, stream>>>(xv, wT_tv, C, C, C, C,
                                            nullptr, vbuf, nullptr, nullptr);
    gemm256<1><<<g256, 512, SMEM, stream>>>(xr, wT_tr, C, C, C, C,
                                            nullptr, rbuf, nullptr, nullptr);

    // segmented exact WKV scan
    const int segthreads = NSEG * C;                     // 524288
    wkv_pp_local<<<segthreads / 256, 256, 0, stream>>>(tdecay, kbuf, pp_loc, C, L);
    wkv_pp_compose<<<(B * C) / 256, 256, 0, stream>>>(tdecay, pp_loc, pp_in, C, SEG, L);
    wkv_ab_local<<<segthreads / 256, 256, 0, stream>>>(tdecay, kbuf, vbuf, pp_in,
                                                       alpha, beta, C, L);
    wkv_aa_compose<<<(B * C) / 256, 256, 0, stream>>>(alpha, beta, aa_in, C, SEG);
    wkv_emit<<<segthreads / 256, 256, 0, stream>>>(tdecay, tfirst, kbuf, vbuf, rbuf,
                                                   aa_in, pp_in, ry, C, L);

    // fused: out = x + ry, then LN2 + shift + channel mixes
    ln_mix_add_b<<<(int)(M / LNR), 256, 0, stream>>>(x, ry, ln2g, ln2b, cmixk, cmixr,
                                                     out, ck, cr, T, C);

    gemm256<1><<<g256, 512, SMEM, stream>>>(cr, wT_cr, C, C, C, C,
                                            nullptr, scr, nullptr, nullptr);

    // channel-mix hidden (4C) processed in two 2C halves through one 64MB buffer
    for (int h = 0; h < 2; ++h) {
        const ushort* wck_h = wT_ck + (long)h * H * C;
        const ushort* wcv_h = (h == 0) ? wT_cv0 : wT_cv1;
        gemm256<2><<<dim3(H / 256, (int)(M / 256)), 512, SMEM, stream>>>(
            ck, wck_h, C, C, C, H, nullptr, kkbuf, nullptr, nullptr);
        gemm256<3><<<g256, 512, SMEM, stream>>>(
            kkbuf, wcv_h, H, H, H, C, out, nullptr, out, scr);
    }
}

// Round 11
// 865.812 us; speedup vs baseline: 1.3331x; 1.0115x over previous
//
#include <hip/hip_runtime.h>
#include <hip/hip_bf16.h>
#include <stdint.h>

#define LN_EPS 1e-5f
#define LNR 8

typedef __attribute__((ext_vector_type(8))) __bf16 bf16x8;
typedef __attribute__((ext_vector_type(8))) short short8;
typedef __attribute__((ext_vector_type(4))) float floatx4;

__device__ __forceinline__ ushort f2bf(float f) {
    __hip_bfloat16 h = __float2bfloat16(f);
    return *reinterpret_cast<ushort*>(&h);
}
__device__ __forceinline__ float bf2f(ushort u) {
    return __builtin_bit_cast(float, ((unsigned int)u) << 16);
}

// async global->LDS, 16B per lane; LDS dest = wave-uniform base + lane*16
__device__ __forceinline__ void gload16(const void* g, void* l) {
#if __has_builtin(__builtin_amdgcn_global_load_lds)
    __builtin_amdgcn_global_load_lds(
        (const __attribute__((address_space(1))) unsigned int*)g,
        (__attribute__((address_space(3))) unsigned int*)l, 16, 0, 0);
#else
    *(int4*)l = *(const int4*)g;
#endif
}

#define SBAR __builtin_amdgcn_s_barrier()
#define SCHED0 __builtin_amdgcn_sched_barrier(0)
#define WAIT_LGKM0 asm volatile("s_waitcnt lgkmcnt(0)" ::: "memory")
#define WAIT_VM4 asm volatile("s_waitcnt vmcnt(4)" ::: "memory")
#define WAIT_VM0 asm volatile("s_waitcnt vmcnt(0)" ::: "memory")

// ---------------------------------------------------------------------------
// GEMM: C[M,N] = A[M,K](bf16 rm, lda) x Bt[N,K](bf16 rm, ldb)  (Bt = B^T)
// 256x256 tile, BK=64, 512 thr (8 waves 2Mx4N, each 128x64 out), 2 MFMA
// phases per K-tile (round-10 measured config).
// ROUND-11 CHANGE: XCD chunking kept, tile decode switched to ROW-major
// (m0=b_/gx) so each XCD chunk = contiguous M-slabs x ALL N-tiles. The gx
// readers of each A-slab then run concurrently on ONE XCD -> A re-reads
// served by its private L2 (per-K-step working set ~384KB << 4MB) instead
// of the shared L3/HBM path. Model: GEMM suite is memory-service-rate
// bound (CU-side 6.22 TB/s == m13 copy ceiling); this moves ~192MB (EPI3)
// off the shared path.
// EPI: 0 bf16 | 1 bf16 sigmoid | 2 bf16 relu^2 | 3 f32 out=add0+mul0*acc
// ---------------------------------------------------------------------------
#define STAGE_A(h, t)                                                        \
    do {                                                                     \
        ushort* _d = &lds[((((t) & 1) * 2 + 0) * 2 + (h)) * 8192];           \
        const long _o = (long)(h) * 128 * lda + (long)(t) * 64;              \
        gload16(aS0 + _o, _d + tid * 8);                                     \
        gload16(aS1 + _o, _d + (tid + 512) * 8);                             \
    } while (0)
#define STAGE_B(h, t)                                                        \
    do {                                                                     \
        ushort* _d = &lds[((((t) & 1) * 2 + 1) * 2 + (h)) * 8192];           \
        const long _o = (long)(h) * 128 * ldb + (long)(t) * 64;              \
        gload16(bS0 + _o, _d + tid * 8);                                     \
        gload16(bS1 + _o, _d + (tid + 512) * 8);                             \
    } while (0)
#define GEMM_LDA(MB)                                                         \
    _Pragma("unroll") for (int mi = 0; mi < 4; ++mi)                         \
    _Pragma("unroll") for (int ks = 0; ks < 2; ++ks)                         \
        a[mi][ks] = __builtin_bit_cast(                                      \
            bf16x8, *(const short8*)&ldsA[((MB) + mi) * 1024 + ks * 512 + aoff]);
#define GEMM_LDB(NB)                                                         \
    _Pragma("unroll") for (int ni = 0; ni < 2; ++ni)                         \
    _Pragma("unroll") for (int ks = 0; ks < 2; ++ks)                         \
        b[(NB) + ni][ks] = __builtin_bit_cast(                               \
            bf16x8, *(const short8*)&ldsB[((NB) + ni) * 1024 + ks * 512 + boff]);
#define GEMM_MFMA(MB, NB)                                                    \
    __builtin_amdgcn_s_setprio(1);                                           \
    _Pragma("unroll") for (int mi = 0; mi < 4; ++mi)                         \
    _Pragma("unroll") for (int ni = 0; ni < 2; ++ni)                         \
    _Pragma("unroll") for (int ks = 0; ks < 2; ++ks)                         \
        acc[(MB) + mi][(NB) + ni] = __builtin_amdgcn_mfma_f32_16x16x32_bf16( \
            a[mi][ks], b[(NB) + ni][ks], acc[(MB) + mi][(NB) + ni], 0, 0, 0);\
    __builtin_amdgcn_s_setprio(0);

template <int EPI>
__global__ __launch_bounds__(512, 2) void gemm256(
    const ushort* __restrict__ A, const ushort* __restrict__ Bt,
    int K, int lda, int ldb, int ldc,
    float* __restrict__ outF, ushort* __restrict__ outB,
    const float* __restrict__ add0, const ushort* __restrict__ mul0) {
    extern __shared__ ushort lds[];

    const int tid  = threadIdx.x;
    const int lane = tid & 63;
    const int quad = lane >> 4;
    const int l16  = lane & 15;
    const int wv   = tid >> 6;      // 0..7
    const int wmi  = wv >> 2;       // 0..1 -> rows wmi*128 (A half = wmi)
    const int wni  = wv & 3;        // 0..3 -> cols wni*64  (B half = wni>>1)

    // XCD-chunked bijective swizzle, ROW-major tile decode:
    // chunk = contiguous M-slabs with all their N-tiles (A-reuse in-XCD-L2).
    const int gx  = gridDim.x;
    const int nwg = gx * gridDim.y;
    int b_ = blockIdx.y * gx + blockIdx.x;
    b_ = (b_ & 7) * (nwg >> 3) + (b_ >> 3);
    const long m0 = (long)(b_ / gx) * 256;
    const long n0 = (long)(b_ % gx) * 256;

    floatx4 acc[8][4];
#pragma unroll
    for (int i = 0; i < 8; ++i)
#pragma unroll
        for (int j = 0; j < 4; ++j) acc[i][j] = (floatx4)0.f;

    // staging slot decode: slot j (16B) -> rowInHalf, col (fragment order)
    const int j1 = tid + 512;
    const int r0 = ((tid >> 7) << 4) + (tid & 15);
    const int c0 = (tid >> 4) & 7;
    const int col0 = (c0 & 3) * 8 + (c0 >> 2) * 32;
    const int r1 = ((j1 >> 7) << 4) + (j1 & 15);
    const int c1 = (j1 >> 4) & 7;
    const int col1 = (c1 & 3) * 8 + (c1 >> 2) * 32;
    const ushort* aS0 = A + (m0 + r0) * (long)lda + col0;
    const ushort* aS1 = A + (m0 + r1) * (long)lda + col1;
    const ushort* bS0 = Bt + (n0 + r0) * (long)ldb + col0;
    const ushort* bS1 = Bt + (n0 + r1) * (long)ldb + col1;

    const int aoff = quad * 128 + l16 * 8;                      // ushort units
    const int boff = (wni & 1) * 4096 + quad * 128 + l16 * 8;

    const int NT = K >> 6;

    // prologue: tile0 {A0,A1,B0,B1} + tile1 {B0,B1}; keep last 2 halves in flight
    STAGE_A(0, 0); STAGE_A(1, 0);
    STAGE_B(0, 0); STAGE_B(1, 0);
    if (NT > 1) { STAGE_B(0, 1); STAGE_B(1, 1); WAIT_VM4; }
    else        { WAIT_VM0; }
    SBAR;

    bf16x8 a[4][2], b[4][2];
    for (int kt = 0; kt < NT; ++kt) {
        const int d = kt & 1;
        const ushort* ldsA = &lds[((d * 2 + 0) * 2 + wmi) * 8192];
        const ushort* ldsB = &lds[((d * 2 + 1) * 2 + (wni >> 1)) * 8192];

        // Phase A: read a0-3 + b0-3 ; stage A0,A1(kt+1) ; MFMA m0-3 x n0-3
        GEMM_LDA(0)
        GEMM_LDB(0)
        GEMM_LDB(2)
        if (kt + 1 < NT) { STAGE_A(0, kt + 1); STAGE_A(1, kt + 1); }
        SBAR; WAIT_LGKM0; SCHED0;
        GEMM_MFMA(0, 0)
        GEMM_MFMA(0, 2)
        SCHED0; SBAR;

        // Phase B: read a4-7 (reuse a regs) ; stage B0,B1(kt+2) ; MFMA m4-7
        // x n0-3 ; counted vmcnt AFTER the cluster (staging hides under MFMA)
        GEMM_LDA(4)
        if (kt + 2 < NT) { STAGE_B(0, kt + 2); STAGE_B(1, kt + 2); }
        SBAR; WAIT_LGKM0; SCHED0;
        GEMM_MFMA(4, 0)
        GEMM_MFMA(4, 2)
        SCHED0;
        if (kt < NT - 2) { WAIT_VM4; } else { WAIT_VM0; }
        SBAR;
    }

    // C/D layout: col = lane&15, row = quad*4 + reg (m89/m91-verified)
#pragma unroll
    for (int mi = 0; mi < 8; ++mi) {
#pragma unroll
        for (int ni = 0; ni < 4; ++ni) {
            const long n = n0 + wni * 64 + ni * 16 + l16;
#pragma unroll
            for (int r = 0; r < 4; ++r) {
                const long m = m0 + wmi * 128 + mi * 16 + quad * 4 + r;
                const long idx = m * (long)ldc + n;
                float v = acc[mi][ni][r];
                if constexpr (EPI == 0) {
                    outB[idx] = f2bf(v);
                } else if constexpr (EPI == 1) {
                    outB[idx] = f2bf(1.f / (1.f + __expf(-v)));
                } else if constexpr (EPI == 2) {
                    float t = fmaxf(v, 0.f);
                    outB[idx] = f2bf(t * t);
                } else if constexpr (EPI == 3) {
                    outF[idx] = add0[idx] + bf2f(mul0[idx]) * v;
                }
            }
        }
    }
}

// ---------------------------------------------------------------------------
// Row-batched LayerNorm + time-shift + mix (3 outputs). Verified (round 9).
// ---------------------------------------------------------------------------
__global__ __launch_bounds__(256) void ln_mix3_b(
    const float* __restrict__ x, const float* __restrict__ g,
    const float* __restrict__ be,
    const float* __restrict__ mx0, const float* __restrict__ mx1,
    const float* __restrict__ mx2,
    ushort* __restrict__ o0, ushort* __restrict__ o1, ushort* __restrict__ o2,
    int T, int C) {
    const long r0 = (long)blockIdx.x * LNR;
    const int tid = threadIdx.x;
    const int i0 = tid * 4;
    const int wv = tid >> 6;
    __shared__ float part[2][4][2];

    const floatx4 gv  = *(const floatx4*)&g[i0];
    const floatx4 bv  = *(const floatx4*)&be[i0];
    const floatx4 mk0 = *(const floatx4*)&mx0[i0];
    const floatx4 mk1 = *(const floatx4*)&mx1[i0];
    const floatx4 mk2 = *(const floatx4*)&mx2[i0];
    const float invC = 1.f / (float)C;

    floatx4 hp = (floatx4)0.f;
    if ((int)(r0 % T) != 0) {
        floatx4 xp = *(const floatx4*)&x[(r0 - 1) * C + i0];
        float s = xp.x + xp.y + xp.z + xp.w;
        float q = xp.x * xp.x + xp.y * xp.y + xp.z * xp.z + xp.w * xp.w;
#pragma unroll
        for (int off = 32; off; off >>= 1) {
            s += __shfl_xor(s, off); q += __shfl_xor(q, off);
        }
        if ((tid & 63) == 0) { part[0][wv][0] = s; part[0][wv][1] = q; }
        __syncthreads();
        s = part[0][0][0] + part[0][1][0] + part[0][2][0] + part[0][3][0];
        q = part[0][0][1] + part[0][1][1] + part[0][2][1] + part[0][3][1];
        float mu = s * invC;
        float rs = rsqrtf(q * invC - mu * mu + LN_EPS);
        hp = (xp - mu) * rs * gv + bv;
        __syncthreads();
    }

    for (int r = 0; r < LNR; ++r) {
        const long row = r0 + r;
        floatx4 xc = *(const floatx4*)&x[row * C + i0];
        float s = xc.x + xc.y + xc.z + xc.w;
        float q = xc.x * xc.x + xc.y * xc.y + xc.z * xc.z + xc.w * xc.w;
#pragma unroll
        for (int off = 32; off; off >>= 1) {
            s += __shfl_xor(s, off); q += __shfl_xor(q, off);
        }
        const int pb = r & 1;
        if ((tid & 63) == 0) { part[pb][wv][0] = s; part[pb][wv][1] = q; }
        __syncthreads();
        s = part[pb][0][0] + part[pb][1][0] + part[pb][2][0] + part[pb][3][0];
        q = part[pb][0][1] + part[pb][1][1] + part[pb][2][1] + part[pb][3][1];
        float mu = s * invC;
        float rs = rsqrtf(q * invC - mu * mu + LN_EPS);
        floatx4 hc = (xc - mu) * rs * gv + bv;

        {
            floatx4 v = hc * mk0 + hp * (1.f - mk0);
            ushort4 pk;
            pk.x = f2bf(v.x); pk.y = f2bf(v.y); pk.z = f2bf(v.z); pk.w = f2bf(v.w);
            *(ushort4*)&o0[row * C + i0] = pk;
        }
        {
            floatx4 v = hc * mk1 + hp * (1.f - mk1);
            ushort4 pk;
            pk.x = f2bf(v.x); pk.y = f2bf(v.y); pk.z = f2bf(v.z); pk.w = f2bf(v.w);
            *(ushort4*)&o1[row * C + i0] = pk;
        }
        {
            floatx4 v = hc * mk2 + hp * (1.f - mk2);
            ushort4 pk;
            pk.x = f2bf(v.x); pk.y = f2bf(v.y); pk.z = f2bf(v.z); pk.w = f2bf(v.w);
            *(ushort4*)&o2[row * C + i0] = pk;
        }
        hp = hc;
    }
}

// ---------------------------------------------------------------------------
// Row-batched: out = x + ry (residual), then LN + shift + 2 mixes.
// Verified (round 9).
// ---------------------------------------------------------------------------
__global__ __launch_bounds__(256) void ln_mix_add_b(
    const float* __restrict__ x, const ushort* __restrict__ ry,
    const float* __restrict__ g, const float* __restrict__ be,
    const float* __restrict__ mx0, const float* __restrict__ mx1,
    float* __restrict__ outx,
    ushort* __restrict__ o0, ushort* __restrict__ o1, int T, int C) {
    const long r0 = (long)blockIdx.x * LNR;
    const int tid = threadIdx.x;
    const int i0 = tid * 4;
    const int wv = tid >> 6;
    __shared__ float part[2][4][2];

    const floatx4 gv  = *(const floatx4*)&g[i0];
    const floatx4 bv  = *(const floatx4*)&be[i0];
    const floatx4 mk0 = *(const floatx4*)&mx0[i0];
    const floatx4 mk1 = *(const floatx4*)&mx1[i0];
    const float invC = 1.f / (float)C;

    floatx4 hp = (floatx4)0.f;
    if ((int)(r0 % T) != 0) {
        floatx4 xp = *(const floatx4*)&x[(r0 - 1) * C + i0];
        ushort4 rp = *(const ushort4*)&ry[(r0 - 1) * C + i0];
        xp.x += bf2f(rp.x); xp.y += bf2f(rp.y); xp.z += bf2f(rp.z); xp.w += bf2f(rp.w);
        float s = xp.x + xp.y + xp.z + xp.w;
        float q = xp.x * xp.x + xp.y * xp.y + xp.z * xp.z + xp.w * xp.w;
#pragma unroll
        for (int off = 32; off; off >>= 1) {
            s += __shfl_xor(s, off); q += __shfl_xor(q, off);
        }
        if ((tid & 63) == 0) { part[0][wv][0] = s; part[0][wv][1] = q; }
        __syncthreads();
        s = part[0][0][0] + part[0][1][0] + part[0][2][0] + part[0][3][0];
        q = part[0][0][1] + part[0][1][1] + part[0][2][1] + part[0][3][1];
        float mu = s * invC;
        float rs = rsqrtf(q * invC - mu * mu + LN_EPS);
        hp = (xp - mu) * rs * gv + bv;
        __syncthreads();
    }

    for (int r = 0; r < LNR; ++r) {
        const long row = r0 + r;
        floatx4 xc = *(const floatx4*)&x[row * C + i0];
        ushort4 rc = *(const ushort4*)&ry[row * C + i0];
        xc.x += bf2f(rc.x); xc.y += bf2f(rc.y); xc.z += bf2f(rc.z); xc.w += bf2f(rc.w);
        *(floatx4*)&outx[row * C + i0] = xc;

        float s = xc.x + xc.y + xc.z + xc.w;
        float q = xc.x * xc.x + xc.y * xc.y + xc.z * xc.z + xc.w * xc.w;
#pragma unroll
        for (int off = 32; off; off >>= 1) {
            s += __shfl_xor(s, off); q += __shfl_xor(q, off);
        }
        const int pb = r & 1;
        if ((tid & 63) == 0) { part[pb][wv][0] = s; part[pb][wv][1] = q; }
        __syncthreads();
        s = part[pb][0][0] + part[pb][1][0] + part[pb][2][0] + part[pb][3][0];
        q = part[pb][0][1] + part[pb][1][1] + part[pb][2][1] + part[pb][3][1];
        float mu = s * invC;
        float rs = rsqrtf(q * invC - mu * mu + LN_EPS);
        floatx4 hc = (xc - mu) * rs * gv + bv;

        {
            floatx4 v = hc * mk0 + hp * (1.f - mk0);
            ushort4 pk;
            pk.x = f2bf(v.x); pk.y = f2bf(v.y); pk.z = f2bf(v.z); pk.w = f2bf(v.w);
            *(ushort4*)&o0[row * C + i0] = pk;
        }
        {
            floatx4 v = hc * mk1 + hp * (1.f - mk1);
            ushort4 pk;
            pk.x = f2bf(v.x); pk.y = f2bf(v.y); pk.z = f2bf(v.z); pk.w = f2bf(v.w);
            *(ushort4*)&o1[row * C + i0] = pk;
        }
        hp = hc;
    }
}

// ===========================================================================
// Segmented exact WKV scan (verified — unchanged).
// ===========================================================================

// K1: per-segment pp from zero state (reads k only)
__global__ __launch_bounds__(256) void wkv_pp_local(
    const float* __restrict__ w, const ushort* __restrict__ k,
    float* __restrict__ pp_loc, int C, int L) {
    const int g = blockIdx.x * 256 + threadIdx.x;
    const int c = g % C;
    const long seg = g / C;
    const float L2E = 1.4426950408889634f;
    const float w2 = w[c] * L2E;
    const ushort* kp = k + seg * L * C + c;
    float pp = -1e38f;
    for (int j = 0; j < L; ++j) {
        float kk = bf2f(kp[(long)j * C]) * L2E;
        float ppw = pp + w2;
        float wk = w2 + kk;
        float p2 = fmaxf(ppw, wk);
        pp = p2 + log2f(exp2f(ppw - p2) + exp2f(wk - p2));
    }
    pp_loc[g] = pp;
}

// K2: sequential pp composition per channel
__global__ __launch_bounds__(256) void wkv_pp_compose(
    const float* __restrict__ w, const float* __restrict__ pp_loc,
    float* __restrict__ pp_in, int C, int SEG, int L) {
    const int g = blockIdx.x * 256 + threadIdx.x;  // b*C + c
    const int c = g % C;
    const long b = g / C;
    const float wL = w[c] * 1.4426950408889634f * (float)L;
    float pp = -1e38f;
    for (int s = 0; s < SEG; ++s) {
        const long idx = (b * SEG + s) * C + c;
        pp_in[idx] = pp;
        float lhs = pp + wL;
        float rhs = pp_loc[idx];
        float m = fmaxf(lhs, rhs);
        pp = m + log2f(exp2f(lhs - m) + exp2f(rhs - m));
    }
}

// K3: per-segment (alpha,beta) on the TRUE pp path
__global__ __launch_bounds__(256) void wkv_ab_local(
    const float* __restrict__ w, const ushort* __restrict__ k,
    const ushort* __restrict__ v, const float* __restrict__ pp_in,
    float* __restrict__ alpha, float* __restrict__ beta, int C, int L) {
    const int g = blockIdx.x * 256 + threadIdx.x;
    const int c = g % C;
    const long seg = g / C;
    const float L2E = 1.4426950408889634f;
    const float w2 = w[c] * L2E;
    const ushort* kp = k + seg * L * C + c;
    const ushort* vp = v + seg * L * C + c;
    float pp = pp_in[g];
    float al = 1.f, be = 0.f;
    for (int j = 0; j < L; ++j) {
        float kk = bf2f(kp[(long)j * C]) * L2E;
        float vv = bf2f(vp[(long)j * C]);
        float ppw = pp + w2;
        float wk = w2 + kk;
        float p2 = fmaxf(ppw, wk);
        float e1u = exp2f(ppw - p2);
        float e2u = exp2f(wk - p2);
        al *= e1u;
        be = e1u * be + e2u * vv;
        pp = p2 + log2f(e1u + e2u);
    }
    alpha[g] = al;
    beta[g] = be;
}

// K4: sequential aa composition per channel
__global__ __launch_bounds__(256) void wkv_aa_compose(
    const float* __restrict__ alpha, const float* __restrict__ beta,
    float* __restrict__ aa_in, int C, int SEG) {
    const int g = blockIdx.x * 256 + threadIdx.x;  // b*C + c
    const int c = g % C;
    const long b = g / C;
    float aa = 0.f;
    for (int s = 0; s < SEG; ++s) {
        const long idx = (b * SEG + s) * C + c;
        aa_in[idx] = aa;
        aa = alpha[idx] * aa + beta[idx];
    }
    (void)c;
}

// K5: per-segment emit with true incoming state: ry = r * y, [M][C] layout
__global__ __launch_bounds__(256) void wkv_emit(
    const float* __restrict__ w, const float* __restrict__ u,
    const ushort* __restrict__ k, const ushort* __restrict__ v,
    const ushort* __restrict__ r, const float* __restrict__ aa_in,
    const float* __restrict__ pp_in, ushort* __restrict__ ry, int C, int L) {
    const int g = blockIdx.x * 256 + threadIdx.x;
    const int c = g % C;
    const long seg = g / C;
    const float L2E = 1.4426950408889634f;
    const float w2 = w[c] * L2E;
    const float u2 = u[c] * L2E;
    const long base = seg * L * C + c;
    const ushort* kp = k + base;
    const ushort* vp = v + base;
    const ushort* rp = r + base;
    ushort* op = ry + base;
    float aa = aa_in[g];
    float pp = pp_in[g];
    for (int j = 0; j < L; ++j) {
        const long o = (long)j * C;
        float kk = bf2f(kp[o]) * L2E;
        float vv = bf2f(vp[o]);
        float uk = u2 + kk;
        float p = fmaxf(pp, uk);
        float e1 = exp2f(pp - p);
        float e2 = exp2f(uk - p);
        float y = __fdividef(e1 * aa + e2 * vv, e1 + e2);
        op[o] = f2bf(bf2f(rp[o]) * y);
        float ppw = pp + w2;
        float wk = w2 + kk;
        float p2 = fmaxf(ppw, wk);
        float e1u = exp2f(ppw - p2);
        float e2u = exp2f(wk - p2);
        aa = e1u * aa + e2u * vv;
        pp = p2 + log2f(e1u + e2u);
    }
}

// out[n][k] = bf16(in[k][n]); in is [K][N] fp32 row-major. block (32,8).
__global__ __launch_bounds__(256) void transpose_bf16(
    const float* __restrict__ in, ushort* __restrict__ out, int K, int N) {
    __shared__ float tile[32][33];
    const int tx = threadIdx.x, ty = threadIdx.y;
    const long k0 = (long)blockIdx.y * 32, n0 = (long)blockIdx.x * 32;
#pragma unroll
    for (int i = 0; i < 4; i++)
        tile[ty + i * 8][tx] = in[(k0 + ty + i * 8) * N + n0 + tx];
    __syncthreads();
#pragma unroll
    for (int i = 0; i < 4; i++)
        out[(n0 + ty + i * 8) * K + k0 + tx] = f2bf(tile[tx][ty + i * 8]);
}

// 4 same-shape (C x C) transposes in one dispatch (blockIdx.z selects pair).
__global__ __launch_bounds__(256) void transpose4_bf16(
    const float* __restrict__ a0, const float* __restrict__ a1,
    const float* __restrict__ a2, const float* __restrict__ a3,
    ushort* __restrict__ b0, ushort* __restrict__ b1,
    ushort* __restrict__ b2, ushort* __restrict__ b3, int K, int N) {
    __shared__ float tile[32][33];
    const int z = blockIdx.z;
    const float* in = (z == 0) ? a0 : (z == 1) ? a1 : (z == 2) ? a2 : a3;
    ushort* out = (z == 0) ? b0 : (z == 1) ? b1 : (z == 2) ? b2 : b3;
    const int tx = threadIdx.x, ty = threadIdx.y;
    const long k0 = (long)blockIdx.y * 32, n0 = (long)blockIdx.x * 32;
#pragma unroll
    for (int i = 0; i < 4; i++)
        tile[ty + i * 8][tx] = in[(k0 + ty + i * 8) * N + n0 + tx];
    __syncthreads();
#pragma unroll
    for (int i = 0; i < 4; i++)
        out[(n0 + ty + i * 8) * K + k0 + tx] = f2bf(tile[tx][ty + i * 8]);
}

extern "C" void kernel_launch(void* const* d_in, const int* in_sizes, int n_in,
                              void* d_out, int out_size, void* d_ws, size_t ws_size,
                              hipStream_t stream) {
    const float* x      = (const float*)d_in[0];
    const float* tdecay = (const float*)d_in[1];
    const float* tfirst = (const float*)d_in[2];
    const float* w_tk   = (const float*)d_in[3];
    const float* w_tv   = (const float*)d_in[4];
    const float* w_tr   = (const float*)d_in[5];
    const float* w_ck   = (const float*)d_in[6];
    const float* w_cv   = (const float*)d_in[7];
    const float* w_cr   = (const float*)d_in[8];
    const float* ln1g   = (const float*)d_in[9];
    const float* ln1b   = (const float*)d_in[10];
    const float* ln2g   = (const float*)d_in[11];
    const float* ln2b   = (const float*)d_in[12];
    const float* mixk   = (const float*)d_in[13];
    const float* mixv   = (const float*)d_in[14];
    const float* mixr   = (const float*)d_in[15];
    const float* cmixk  = (const float*)d_in[16];
    const float* cmixr  = (const float*)d_in[17];
    float* out = (float*)d_out;

    const int C  = in_sizes[1];              // 1024
    const long M = (long)in_sizes[0] / C;    // 16384
    const int T  = 2048;
    const int B  = (int)(M / T);
    const int H  = 2 * C;                    // 2048 = half of 4C
    const int SEG = 64;                      // segments per sequence
    const int L  = T / SEG;                  // 32 steps per segment
    const int NSEG = B * SEG;                // 512 total segments

    // one-time: allow 128 KiB dynamic LDS for gemm256
    static bool s_attr = []() {
        (void)hipFuncSetAttribute((const void*)gemm256<0>,
                                  hipFuncAttributeMaxDynamicSharedMemorySize, 131072);
        (void)hipFuncSetAttribute((const void*)gemm256<1>,
                                  hipFuncAttributeMaxDynamicSharedMemorySize, 131072);
        (void)hipFuncSetAttribute((const void*)gemm256<2>,
                                  hipFuncAttributeMaxDynamicSharedMemorySize, 131072);
        (void)hipFuncSetAttribute((const void*)gemm256<3>,
                                  hipFuncAttributeMaxDynamicSharedMemorySize, 131072);
        return true;
    }();
    (void)s_attr;
    const int SMEM = 131072;

    // workspace layout identical to previous (verified) version
    const size_t MBy = 1024ull * 1024ull;
    char* w8 = (char*)d_ws;
    ushort* wT_tk  = (ushort*)(w8 + 0 * MBy);
    ushort* wT_tv  = (ushort*)(w8 + 2 * MBy);
    ushort* wT_tr  = (ushort*)(w8 + 4 * MBy);
    ushort* wT_cr  = (ushort*)(w8 + 6 * MBy);
    ushort* wT_ck  = (ushort*)(w8 + 8 * MBy);
    ushort* wT_cv0 = (ushort*)(w8 + 16 * MBy);
    ushort* wT_cv1 = (ushort*)(w8 + 20 * MBy);
    ushort* xk     = (ushort*)(w8 + 24 * MBy);
    ushort* xv     = (ushort*)(w8 + 56 * MBy);
    ushort* xr     = (ushort*)(w8 + 88 * MBy);
    ushort* kbuf   = (ushort*)(w8 + 120 * MBy);
    ushort* vbuf   = (ushort*)(w8 + 152 * MBy);
    ushort* rbuf   = (ushort*)(w8 + 24 * MBy);   // xk dead
    float*  pp_loc = (float*)(w8 + 56 * MBy);    // xv dead (2MB each)
    float*  pp_in  = (float*)(w8 + 58 * MBy);
    float*  alpha  = (float*)(w8 + 60 * MBy);
    float*  beta   = (float*)(w8 + 62 * MBy);
    float*  aa_in  = (float*)(w8 + 64 * MBy);
    ushort* ry     = (ushort*)(w8 + 88 * MBy);   // xr dead
    ushort* ck     = (ushort*)(w8 + 120 * MBy);  // kbuf dead
    ushort* cr     = (ushort*)(w8 + 152 * MBy);  // vbuf dead
    ushort* scr    = (ushort*)(w8 + 24 * MBy);   // rbuf dead
    ushort* kkbuf  = (ushort*)(w8 + 56 * MBy);   // states/ry dead, 64MB

    dim3 tb(32, 8);
    transpose4_bf16<<<dim3(C / 32, C / 32, 4), tb, 0, stream>>>(
        w_tk, w_tv, w_tr, w_cr, wT_tk, wT_tv, wT_tr, wT_cr, C, C);
    transpose_bf16<<<dim3(4 * C / 32, C / 32), tb, 0, stream>>>(w_ck, wT_ck, C, 4 * C);
    transpose_bf16<<<dim3(C / 32, H / 32), tb, 0, stream>>>(w_cv, wT_cv0, H, C);
    transpose_bf16<<<dim3(C / 32, H / 32), tb, 0, stream>>>(w_cv + (long)H * C, wT_cv1, H, C);

    ln_mix3_b<<<(int)(M / LNR), 256, 0, stream>>>(x, ln1g, ln1b, mixk, mixv, mixr,
                                                  xk, xv, xr, T, C);

    dim3 g256(C / 256, (int)(M / 256));
    gemm256<0><<<g256, 512, SMEM, stream>>>(xk, wT_tk, C, C, C, C,
                                            nullptr, kbuf, nullptr, nullptr);
    gemm256<0><<<g256, 512, SMEM, stream>>>(xv, wT_tv, C, C, C, C,
                                            nullptr, vbuf, nullptr, nullptr);
    gemm256<1><<<g256, 512, SMEM, stream>>>(xr, wT_tr, C, C, C, C,
                                            nullptr, rbuf, nullptr, nullptr);

    // segmented exact WKV scan
    const int segthreads = NSEG * C;                     // 524288
    wkv_pp_local<<<segthreads / 256, 256, 0, stream>>>(tdecay, kbuf, pp_loc, C, L);
    wkv_pp_compose<<<(B * C) / 256, 256, 0, stream>>>(tdecay, pp_loc, pp_in, C, SEG, L);
    wkv_ab_local<<<segthreads / 256, 256, 0, stream>>>(tdecay, kbuf, vbuf, pp_in,
                                                       alpha, beta, C, L);
    wkv_aa_compose<<<(B * C) / 256, 256, 0, stream>>>(alpha, beta, aa_in, C, SEG);
    wkv_emit<<<segthreads / 256, 256, 0, stream>>>(tdecay, tfirst, kbuf, vbuf, rbuf,
                                                   aa_in, pp_in, ry, C, L);

    // fused: out = x + ry, then LN2 + shift + channel mixes
    ln_mix_add_b<<<(int)(M / LNR), 256, 0, stream>>>(x, ry, ln2g, ln2b, cmixk, cmixr,
                                                     out, ck, cr, T, C);

    gemm256<1><<<g256, 512, SMEM, stream>>>(cr, wT_cr, C, C, C, C,
                                            nullptr, scr, nullptr, nullptr);

    // channel-mix hidden (4C) processed in two 2C halves through one 64MB buffer
    for (int h = 0; h < 2; ++h) {
        const ushort* wck_h = wT_ck + (long)h * H * C;
        const ushort* wcv_h = (h == 0) ? wT_cv0 : wT_cv1;
        gemm256<2><<<dim3(H / 256, (int)(M / 256)), 512, SMEM, stream>>>(
            ck, wck_h, C, C, C, H, nullptr, kkbuf, nullptr, nullptr);
        gemm256<3><<<g256, 512, SMEM, stream>>>(
            kkbuf, wcv_h, H, H, H, C, out, nullptr, out, scr);
    }
}